// Round 5
// baseline (491.035 us; speedup 1.0000x reference)
//
#include <hip/hip_runtime.h>
#include <hip/hip_bf16.h>

using f16 = _Float16;
typedef __attribute__((ext_vector_type(8))) f16 half8;
typedef __attribute__((ext_vector_type(4))) f16 half4;
typedef __attribute__((ext_vector_type(4))) float floatx4;

#define LN_EPS 1e-5f

// ---------------------------------------------------------------------------
// async global->LDS, 16B per lane. LDS dest is wave-uniform base + lane*16.
// ---------------------------------------------------------------------------
__device__ __forceinline__ void gload_lds16(const f16* g, f16* l) {
  __builtin_amdgcn_global_load_lds(
      (const __attribute__((address_space(1))) void*)g,
      (__attribute__((address_space(3))) void*)l, 16, 0, 0);
}

#define CFENCE asm volatile("" ::: "memory")
#define WAIT_VM(N) asm volatile("s_waitcnt vmcnt(" #N ")" ::: "memory")
#define WAIT_LGKM0                                     \
  do {                                                 \
    asm volatile("s_waitcnt lgkmcnt(0)" ::: "memory"); \
    __builtin_amdgcn_sched_barrier(0);                 \
  } while (0)
#define BARRIER()                    \
  do {                               \
    CFENCE;                          \
    __builtin_amdgcn_s_barrier();    \
    CFENCE;                          \
  } while (0)

// ---------------------------------------------------------------------------
// 256x256-tile 8-phase pipelined GEMM core (T1+T2+T3+T4+T5), 512 thr
// (8 waves, 2Mx4N), BK=64, per-wave output 128x64 (acc[8][4] f32x4),
// 128 KiB LDS (2 K-tile buffers x (A 256x64 + B 256x64) f16).
// Schedule identical to the round-1 harness-verified kernel.
// EPI: 1 = f16 store; 2 = bias+relu; 3 = f16 store + softmax partial stats
// (per-row max / exp-sum over this wave's 64-col chunk -> Smax/Ssum).
// ---------------------------------------------------------------------------
template <int EPI>
__device__ __forceinline__ void gemm256_core(
    const f16* __restrict__ A, const f16* __restrict__ B,
    f16* __restrict__ Cz, const float* __restrict__ bias,
    int lda, int ldb, int ldc, int kper, int kbeg, int bm, int bn,
    f16* smp, float* __restrict__ Smax, float* __restrict__ Ssum) {
  const int t = threadIdx.x;
  const int wave = t >> 6, lane = t & 63;
  const int wm = (wave >> 2) << 7;  // wave M offset: 0/128
  const int wn = (wave & 3) << 6;   // wave N offset: 0/64/128/192
  const int lrow = lane & 15, lkc = lane >> 4;

  // staging: seg = wave*2+l covers 8 rows of a 128-row half-tile
  const int srow = lane >> 3;
  const int schunk = ((lane & 7) ^ srow) << 3;  // swizzled source chunk (elems)
  const f16* Ag = A + (size_t)(bm + wave * 16 + srow) * lda + kbeg + schunk;
  const f16* Bg = B + (size_t)(bn + wave * 16 + srow) * ldb + kbeg + schunk;

  // swizzled fragment k-offsets (elems within 64-elem row), kk = 0 / 1
  const int co0 = ((lkc ^ (lrow & 7)) << 3);
  const int co1 = (((4 + lkc) ^ (lrow & 7)) << 3);

  floatx4 acc[8][4] = {};
  half8 af[4][2];       // one qm-half of A frags, both kk
  half8 bf[2][2][2];    // [qn][fn][kk] -- both qn halves live

  auto STAGE = [&](int b, int tt, int h) {  // h: 0=A-lo 1=A-hi 2=B-lo 3=B-hi
    if (h < 2) {
      const f16* src = Ag + (size_t)(h * 128) * lda + tt * 64;
      f16* d = smp + (b * 2) * 16384 + h * 8192 + wave * 1024;
      gload_lds16(src, d);
      gload_lds16(src + (size_t)8 * lda, d + 512);
    } else {
      const f16* src = Bg + (size_t)((h - 2) * 128) * ldb + tt * 64;
      f16* d = smp + (b * 2 + 1) * 16384 + (h - 2) * 8192 + wave * 1024;
      gload_lds16(src, d);
      gload_lds16(src + (size_t)8 * ldb, d + 512);
    }
  };
  auto LDA = [&](int b, int qm) {
    const f16* base = smp + (b * 2) * 16384 + (wm + qm * 64 + lrow) * 64;
#pragma unroll
    for (int fm = 0; fm < 4; ++fm) {
      af[fm][0] = *(const half8*)(base + fm * (16 * 64) + co0);
      af[fm][1] = *(const half8*)(base + fm * (16 * 64) + co1);
    }
  };
  auto LDB = [&](int b, int qn) {
    const f16* base = smp + (b * 2 + 1) * 16384 + (wn + qn * 32 + lrow) * 64;
#pragma unroll
    for (int fn = 0; fn < 2; ++fn) {
      bf[qn][fn][0] = *(const half8*)(base + fn * (16 * 64) + co0);
      bf[qn][fn][1] = *(const half8*)(base + fn * (16 * 64) + co1);
    }
  };
  auto MFMAQ = [&](int qm, int qn) {
    __builtin_amdgcn_s_setprio(1);
#pragma unroll
    for (int kk = 0; kk < 2; ++kk)
#pragma unroll
      for (int fm = 0; fm < 4; ++fm)
#pragma unroll
        for (int fn = 0; fn < 2; ++fn)
          acc[qm * 4 + fm][qn * 2 + fn] =
              __builtin_amdgcn_mfma_f32_16x16x32_f16(
                  af[fm][kk], bf[qn][fn][kk], acc[qm * 4 + fm][qn * 2 + fn],
                  0, 0, 0);
    __builtin_amdgcn_s_setprio(0);
  };

  const int NT = kper >> 6;  // K-tiles (even for all call sites)
  const int NI = NT >> 1;

  // prologue: tile0 -> buf0 (4 halves), tile1 half0 -> buf1; wait tile0
  STAGE(0, 0, 0); STAGE(0, 0, 1); STAGE(0, 0, 2); STAGE(0, 0, 3);
  STAGE(1, 1, 0);
  WAIT_VM(2);
  BARRIER();

  for (int i = 0; i < NI; ++i) {
    const bool last = (i == NI - 1);
    const int tb = 2 * i;
    // P0 -- t0 Q(0,0)
    LDA(0, 0); LDB(0, 0); STAGE(1, tb + 1, 1);
    BARRIER(); MFMAQ(0, 0); BARRIER();
    // P1 -- t0 Q(0,1)
    LDB(0, 1); STAGE(1, tb + 1, 2);
    BARRIER(); MFMAQ(0, 1); BARRIER();
    // P2 -- t0 Q(1,0)
    LDA(0, 1); STAGE(1, tb + 1, 3);
    BARRIER(); MFMAQ(1, 0); BARRIER();
    // P3 -- t0 Q(1,1); guarantee tile t1 landed before P4 reads buf1
    if (!last) {
      STAGE(0, tb + 2, 0);
      WAIT_VM(2);
    } else {
      WAIT_VM(0);
    }
    BARRIER(); MFMAQ(1, 1); BARRIER();
    // P4 -- t1 Q(0,0)
    LDA(1, 0); LDB(1, 0);
    if (!last) STAGE(0, tb + 2, 1);
    BARRIER(); MFMAQ(0, 0); BARRIER();
    // P5 -- t1 Q(0,1)
    LDB(1, 1);
    if (!last) STAGE(0, tb + 2, 2);
    BARRIER(); MFMAQ(0, 1); BARRIER();
    // P6 -- t1 Q(1,0)
    LDA(1, 1);
    if (!last) STAGE(0, tb + 2, 3);
    BARRIER(); MFMAQ(1, 0); BARRIER();
    // P7 -- t1 Q(1,1); guarantee tile t0+2 landed before next P0 reads buf0
    if (!last) {
      STAGE(1, tb + 3, 0);
      WAIT_VM(2);
    }
    BARRIER(); MFMAQ(1, 1); BARRIER();
  }

  // epilogue: C/D col = lane&15, row = (lane>>4)*4 + reg
  const int crow0 = bm + wm + lkc * 4;
  const int ccol0 = bn + wn + lrow;
#pragma unroll
  for (int i = 0; i < 8; ++i) {
#pragma unroll
    for (int r2 = 0; r2 < 4; ++r2) {
      const size_t row = (size_t)(crow0 + i * 16 + r2);
#pragma unroll
      for (int j = 0; j < 4; ++j) {
        const int col = ccol0 + j * 16;
        float v = acc[i][j][r2];
        if (EPI == 2) v = fmaxf(v + bias[col], 0.0f);
        Cz[row * (size_t)ldc + col] = (f16)v;
      }
    }
  }
  if (EPI == 3) {
    // softmax partial stats: per row, max & exp-sum over this wave's 64 cols
    const int chunk = (bn + wn) >> 6;  // 0..63
#pragma unroll
    for (int i = 0; i < 8; ++i) {
#pragma unroll
      for (int r2 = 0; r2 < 4; ++r2) {
        float mx = fmaxf(fmaxf(acc[i][0][r2], acc[i][1][r2]),
                         fmaxf(acc[i][2][r2], acc[i][3][r2]));
#pragma unroll
        for (int m_ = 8; m_ >= 1; m_ >>= 1) mx = fmaxf(mx, __shfl_xor(mx, m_));
        float s = 0.0f;
#pragma unroll
        for (int j = 0; j < 4; ++j) s += __expf(acc[i][j][r2] - mx);
#pragma unroll
        for (int m_ = 8; m_ >= 1; m_ >>= 1) s += __shfl_xor(s, m_);
        if (lrow == 0) {
          const int row = crow0 + i * 16 + r2;
          Smax[(size_t)row * 64 + chunk] = mx;
          Ssum[(size_t)row * 64 + chunk] = s;
        }
      }
    }
  }
}

// bijective XCD-chunked swizzle (T1).
__device__ __forceinline__ int xcd_swizzle(int id, int nwg) {
  const int q = nwg >> 3, r = nwg & 7;
  const int xcd = id & 7, lin = id >> 3;
  return (xcd < r ? xcd * (q + 1) : r * (q + 1) + (xcd - r) * q) + lin;
}

// ---------------------------------------------------------------------------
// generic NT wrapper: C = A*B^T, split-K via gridDim.z, f16 slabs at
// Ch + z*M*ldc. EPI=3 additionally writes softmax partial stats.
// ---------------------------------------------------------------------------
template <int EPI>
__global__ __launch_bounds__(512, 2) void gemm_nt256(
    const f16* __restrict__ A, const f16* __restrict__ B,
    f16* __restrict__ Ch, const float* __restrict__ bias,
    float* __restrict__ Smax, float* __restrict__ Ssum,
    int M, int Nc, int K, int lda, int ldb, int ldc) {
  __shared__ f16 sm[4][256 * 64];
  const int gx = gridDim.x, gy = gridDim.y;
  const int nwg = gx * gy * gridDim.z;
  const int id = blockIdx.x + gx * (blockIdx.y + gy * blockIdx.z);
  const int nid = xcd_swizzle(id, nwg);
  const int bx = nid % gx;
  const int by = (nid / gx) % gy;
  const int bz = nid / (gx * gy);
  const int kper = K / gridDim.z;
  gemm256_core<EPI>(A, B, Ch + (size_t)bz * M * ldc, bias, lda, ldb, ldc,
                    kper, bz * kper, by << 8, bx << 8, &sm[0][0], Smax, Ssum);
}

// ---------------------------------------------------------------------------
// weight precompose on the 8-phase core: grid (4,4,16).
// ---------------------------------------------------------------------------
__global__ __launch_bounds__(512, 2) void gemm_pre256(
    const f16* __restrict__ Wkb, const f16* __restrict__ Wqb,
    const f16* __restrict__ WoT, const f16* __restrict__ Wvb,
    f16* __restrict__ parQK, f16* __restrict__ parVO, int D, int H) {
  __shared__ f16 sm[4][256 * 64];
  const int id = blockIdx.x + 4 * (blockIdx.y + 4 * blockIdx.z);
  const int nid = xcd_swizzle(id, 256);
  const int bx = nid & 3, by = (nid >> 2) & 3, z = nid >> 4;
  const int zz = z & 7;
  const f16* A = (z < 8) ? Wkb : WoT;
  const f16* B = (z < 8) ? Wqb : Wvb;
  f16* slab = ((z < 8) ? parQK : parVO) + (size_t)zz * D * D;
  gemm256_core<1>(A, B, slab, nullptr, H, H, D, H / 8, zz * (H / 8),
                  by << 8, bx << 8, &sm[0][0], nullptr, nullptr);
}

// ---------------------------------------------------------------------------
// merged th/xvoT on the 8-phase core: grid (4,32).
// ---------------------------------------------------------------------------
__global__ __launch_bounds__(512, 2) void gemm_dual256(
    const f16* __restrict__ xb, const f16* __restrict__ WqkT,
    const f16* __restrict__ WvoT, f16* __restrict__ th,
    f16* __restrict__ xvoT, int N, int D) {
  __shared__ f16 sm[4][256 * 64];
  const int id = blockIdx.x + 4 * blockIdx.y;
  const int nid = xcd_swizzle(id, 128);
  const int bx = nid & 3, y = nid >> 2;
  if (y < 16)
    gemm256_core<1>(xb, WqkT, th, nullptr, D, D, D, D, 0,
                    y << 8, bx << 8, &sm[0][0], nullptr, nullptr);
  else
    gemm256_core<1>(WvoT, xb, xvoT, nullptr, D, D, N, D, 0,
                    bx << 8, (y - 16) << 8, &sm[0][0], nullptr, nullptr);
}

// ---------------------------------------------------------------------------
// PV GEMM with fused softmax on the A operand: attn = softmax(S) @ xvoT^T.
// Same 8-phase schedule/vmcnt counts as gemm256_core; A staging is
// reg-loaded (2 VMEM per stage, like gload) and exp((s-m))*inv is applied
// at the ds_write points (P3/P7, after the counted WAIT_VM that proves the
// loads landed; +lgkmcnt(0) publish before the barrier). rowstat[row] =
// (rowmax m, 1/sum). Fixed pending regs pC/pend0/pend1 rotate with period 8.
// ---------------------------------------------------------------------------
__global__ __launch_bounds__(512, 2) void gemm_pv256(
    const f16* __restrict__ A, const f16* __restrict__ B,
    f16* __restrict__ Ch, const float2* __restrict__ rowstat,
    int M, int Nc, int K, int lda, int ldb, int ldc) {
  __shared__ f16 sm[4][256 * 64];
  f16* smp = &sm[0][0];
  const int gx = gridDim.x, gy = gridDim.y;
  const int nwg = gx * gy * gridDim.z;
  const int id = blockIdx.x + gx * (blockIdx.y + gy * blockIdx.z);
  const int nid = xcd_swizzle(id, nwg);
  const int bx = nid % gx;
  const int by = (nid / gx) % gy;
  const int bz = nid / (gx * gy);
  const int kper = K / gridDim.z;
  const int kbeg = bz * kper;
  f16* Cz = Ch + (size_t)bz * M * ldc;
  const int bm = by << 8, bn = bx << 8;

  const int t = threadIdx.x;
  const int wave = t >> 6, lane = t & 63;
  const int wm = (wave >> 2) << 7;
  const int wn = (wave & 3) << 6;
  const int lrow = lane & 15, lkc = lane >> 4;
  const int srow = lane >> 3;
  const int schunk = ((lane & 7) ^ srow) << 3;
  const f16* Ag = A + (size_t)(bm + wave * 16 + srow) * lda + kbeg + schunk;
  const f16* Bg = B + (size_t)(bn + wave * 16 + srow) * ldb + kbeg + schunk;
  const int co0 = ((lkc ^ (lrow & 7)) << 3);
  const int co1 = (((4 + lkc) ^ (lrow & 7)) << 3);

  // preload softmax row stats for the 4 rows this lane stages
  const int r0s = bm + wave * 16 + srow;
  const float2 st00 = rowstat[r0s], st01 = rowstat[r0s + 8];
  const float2 st10 = rowstat[r0s + 128], st11 = rowstat[r0s + 136];

  floatx4 acc[8][4] = {};
  half8 af[4][2];
  half8 bf[2][2][2];
  half8 pCa, pCb, p0a, p0b, p1a, p1b;  // pending A (h0-type: pC,p0; h1: p1)

  auto ALOAD = [&](int tt, int h, half8& ra, half8& rb) {
    const f16* src = Ag + (size_t)(h * 128) * lda + tt * 64;
    ra = *(const half8*)(src);
    rb = *(const half8*)(src + (size_t)8 * lda);
  };
  auto AWRITE = [&](int b, int h, const half8& ra, const half8& rb,
                    const float2& sa, const float2& sb) {
    f16* d = smp + (b * 2) * 16384 + h * 8192 + wave * 1024 + lane * 8;
    half8 oa, ob;
#pragma unroll
    for (int k = 0; k < 8; ++k) {
      oa[k] = (f16)(__expf((float)ra[k] - sa.x) * sa.y);
      ob[k] = (f16)(__expf((float)rb[k] - sb.x) * sb.y);
    }
    *(half8*)d = oa;
    *(half8*)(d + 512) = ob;
  };
  auto BSTAGE = [&](int b, int tt, int h) {  // h: 2=B-lo 3=B-hi
    const f16* src = Bg + (size_t)((h - 2) * 128) * ldb + tt * 64;
    f16* d = smp + (b * 2 + 1) * 16384 + (h - 2) * 8192 + wave * 1024;
    gload_lds16(src, d);
    gload_lds16(src + (size_t)8 * ldb, d + 512);
  };
  auto LDA = [&](int b, int qm) {
    const f16* base = smp + (b * 2) * 16384 + (wm + qm * 64 + lrow) * 64;
#pragma unroll
    for (int fm = 0; fm < 4; ++fm) {
      af[fm][0] = *(const half8*)(base + fm * (16 * 64) + co0);
      af[fm][1] = *(const half8*)(base + fm * (16 * 64) + co1);
    }
  };
  auto LDB = [&](int b, int qn) {
    const f16* base = smp + (b * 2 + 1) * 16384 + (wn + qn * 32 + lrow) * 64;
#pragma unroll
    for (int fn = 0; fn < 2; ++fn) {
      bf[qn][fn][0] = *(const half8*)(base + fn * (16 * 64) + co0);
      bf[qn][fn][1] = *(const half8*)(base + fn * (16 * 64) + co1);
    }
  };
  auto MFMAQ = [&](int qm, int qn) {
    __builtin_amdgcn_s_setprio(1);
#pragma unroll
    for (int kk = 0; kk < 2; ++kk)
#pragma unroll
      for (int fm = 0; fm < 4; ++fm)
#pragma unroll
        for (int fn = 0; fn < 2; ++fn)
          acc[qm * 4 + fm][qn * 2 + fn] =
              __builtin_amdgcn_mfma_f32_16x16x32_f16(
                  af[fm][kk], bf[qn][fn][kk], acc[qm * 4 + fm][qn * 2 + fn],
                  0, 0, 0);
    __builtin_amdgcn_s_setprio(0);
  };

  const int NT = kper >> 6;
  const int NI = NT >> 1;

  // prologue: t0 A->pC/p1, t0 B gload, t1.h0 A->p0; wait; write t0 A; barrier
  ALOAD(0, 0, pCa, pCb);
  ALOAD(0, 1, p1a, p1b);
  BSTAGE(0, 0, 2); BSTAGE(0, 0, 3);
  ALOAD(1, 0, p0a, p0b);
  WAIT_VM(2);
  AWRITE(0, 0, pCa, pCb, st00, st01);
  AWRITE(0, 1, p1a, p1b, st10, st11);
  WAIT_LGKM0;
  BARRIER();

  for (int i = 0; i < NI; ++i) {
    const bool last = (i == NI - 1);
    const int tb = 2 * i;
    // P0
    LDA(0, 0); LDB(0, 0); ALOAD(tb + 1, 1, p1a, p1b);
    BARRIER(); MFMAQ(0, 0); BARRIER();
    // P1
    LDB(0, 1); BSTAGE(1, tb + 1, 2);
    BARRIER(); MFMAQ(0, 1); BARRIER();
    // P2
    LDA(0, 1); BSTAGE(1, tb + 1, 3);
    BARRIER(); MFMAQ(1, 0); BARRIER();
    // P3 -- write t1 A into buf1 (loads proven landed by counted wait)
    if (!last) {
      ALOAD(tb + 2, 0, pCa, pCb);
      WAIT_VM(2);
    } else {
      WAIT_VM(0);
    }
    AWRITE(1, 0, p0a, p0b, st00, st01);
    AWRITE(1, 1, p1a, p1b, st10, st11);
    WAIT_LGKM0;
    BARRIER(); MFMAQ(1, 1); BARRIER();
    // P4
    LDA(1, 0); LDB(1, 0);
    if (!last) ALOAD(tb + 2, 1, p1a, p1b);
    BARRIER(); MFMAQ(0, 0); BARRIER();
    // P5
    LDB(1, 1);
    if (!last) BSTAGE(0, tb + 2, 2);
    BARRIER(); MFMAQ(0, 1); BARRIER();
    // P6
    LDA(1, 1);
    if (!last) BSTAGE(0, tb + 2, 3);
    BARRIER(); MFMAQ(1, 0); BARRIER();
    // P7 -- write t2 A into buf0
    if (!last) {
      ALOAD(tb + 3, 0, p0a, p0b);
      WAIT_VM(2);
      AWRITE(0, 0, pCa, pCb, st00, st01);
      AWRITE(0, 1, p1a, p1b, st10, st11);
      WAIT_LGKM0;
    }
    BARRIER(); MFMAQ(1, 1); BARRIER();
  }

  // epilogue
  const int crow0 = bm + wm + lkc * 4;
  const int ccol0 = bn + wn + lrow;
#pragma unroll
  for (int i = 0; i < 8; ++i) {
#pragma unroll
    for (int r2 = 0; r2 < 4; ++r2) {
      const size_t row = (size_t)(crow0 + i * 16 + r2);
#pragma unroll
      for (int j = 0; j < 4; ++j)
        Cz[row * (size_t)ldc + ccol0 + j * 16] = (f16)acc[i][j][r2];
    }
  }
}

// ---------------------------------------------------------------------------
// combine softmax partials: per row, m = max(mp), s = sum(sp*exp(mp-m));
// rowstat[row] = (m, 1/s). grid 1024 x 256 thr (4 rows/block).
// ---------------------------------------------------------------------------
__global__ void smax_reduce(const float* __restrict__ Smax,
                            const float* __restrict__ Ssum,
                            float2* __restrict__ rowstat) {
  const int row = blockIdx.x * 4 + (threadIdx.x >> 6);
  const int c = threadIdx.x & 63;
  const float mp = Smax[(size_t)row * 64 + c];
  const float sp = Ssum[(size_t)row * 64 + c];
  float m = mp;
#pragma unroll
  for (int off = 32; off > 0; off >>= 1) m = fmaxf(m, __shfl_xor(m, off));
  float s = sp * __expf(mp - m);
#pragma unroll
  for (int off = 32; off > 0; off >>= 1) s += __shfl_xor(s, off);
  if (c == 0) rowstat[row] = make_float2(m, 1.0f / s);
}

// ---------------------------------------------------------------------------
// fused input prep (round-3 verified variant), grid (1024, 7), block 256.
// ---------------------------------------------------------------------------
__global__ void prep_inputs(const float* x, const float* Wq, const float* Wk,
                            const float* Wv, const float* W1, const float* Wo,
                            const float* W2, f16* xb, f16* Wqb, f16* Wkb,
                            f16* Wvb, f16* W1T, f16* WoT, f16* W2T) {
  const int z = blockIdx.y;
  const int b = blockIdx.x;
  const int t = threadIdx.x;
  if (z >= 3) {  // converts: 4M elems each, 1024 blocks x 256 thr x 16 elems
    const float* in = (z == 3) ? x : (z == 4) ? Wq : (z == 5) ? Wk : Wv;
    f16* out = (z == 3) ? xb : (z == 4) ? Wqb : (z == 5) ? Wkb : Wvb;
    const size_t i = ((size_t)b * 256 + t) * 16;
    const float4 a0 = *(const float4*)(in + i);
    const float4 a1 = *(const float4*)(in + i + 4);
    const float4 a2 = *(const float4*)(in + i + 8);
    const float4 a3 = *(const float4*)(in + i + 12);
    half8 v0 = {(f16)a0.x, (f16)a0.y, (f16)a0.z, (f16)a0.w,
                (f16)a1.x, (f16)a1.y, (f16)a1.z, (f16)a1.w};
    half8 v1 = {(f16)a2.x, (f16)a2.y, (f16)a2.z, (f16)a2.w,
                (f16)a3.x, (f16)a3.y, (f16)a3.z, (f16)a3.w};
    *(half8*)(out + i) = v0;
    *(half8*)(out + i + 8) = v1;
    return;
  }
  int R, C, tx, ty;
  const float* in;
  f16* out;
  if (z == 0) {
    R = 1024; C = 4096; in = W1; out = W1T;
    tx = b & 63; ty = b >> 6;
  } else {
    R = 4096; C = 1024; in = (z == 1) ? Wo : W2;
    out = (z == 1) ? WoT : W2T;
    tx = b & 15; ty = b >> 4;
  }
  const int r0 = ty << 6, c0 = tx << 6;
  __shared__ f16 lt[64 * 64];
  const int lr = t >> 4;
  const int lc = t & 15;
  const int q3 = lr & 3;
  const int rb = lr & ~3;
  const int myc = lc * 4 + q3;
#pragma unroll
  for (int rr = 0; rr < 4; ++rr) {
    const int r = lr + rr * 16;
    const float4 f = *(const float4*)(in + (size_t)(r0 + r) * C + c0 + lc * 4);
    float v0 = f.x, v1 = f.y, v2 = f.z, v3 = f.w;
    {
      const bool hi = (q3 & 2) != 0;
      float sA = hi ? v0 : v2;
      float sB = hi ? v1 : v3;
      sA = __shfl_xor(sA, 32);
      sB = __shfl_xor(sB, 32);
      if (hi) { v0 = sA; v1 = sB; } else { v2 = sA; v3 = sB; }
    }
    {
      const bool od = (q3 & 1) != 0;
      float sC = od ? v0 : v1;
      float sD = od ? v2 : v3;
      sC = __shfl_xor(sC, 16);
      sD = __shfl_xor(sD, 16);
      if (od) { v0 = sC; v2 = sD; } else { v1 = sC; v3 = sD; }
    }
    half4 hv = {(f16)v0, (f16)v1, (f16)v2, (f16)v3};
    const int rbase = rb + rr * 16;
    *(half4*)(lt + myc * 64 + (rbase ^ ((myc & 15) << 2))) = hv;
  }
  __syncthreads();
  const int oc = t >> 3, orr = (t & 7) << 3;
#pragma unroll
  for (int cc = 0; cc < 2; ++cc) {
    const int c = oc + cc * 32;
    const int swz = (c & 15) << 2;
    const half4 ha = *(const half4*)(lt + c * 64 + (orr ^ swz));
    const half4 hb4 = *(const half4*)(lt + c * 64 + ((orr + 4) ^ swz));
    half8 v = {ha[0], ha[1], ha[2], ha[3], hb4[0], hb4[1], hb4[2], hb4[3]};
    *(half8*)(out + (size_t)(c0 + c) * R + r0 + orr) = v;
  }
}

// ---------------------------------------------------------------------------
// merged slab reduce: 16B/lane loads.
// ---------------------------------------------------------------------------
__global__ void reduce_dual(const f16* __restrict__ parQK,
                            const f16* __restrict__ parVO,
                            f16* __restrict__ WqkT, f16* __restrict__ WvoT,
                            int n) {
  const int half = gridDim.x >> 1;
  const bool second = blockIdx.x >= half;
  const f16* par = second ? parVO : parQK;
  f16* out = second ? WvoT : WqkT;
  const int b = second ? blockIdx.x - half : blockIdx.x;
  const int i = (b * 256 + threadIdx.x) * 8;
  float s[8] = {};
#pragma unroll
  for (int z = 0; z < 8; ++z) {
    const half8 p = *(const half8*)(par + (size_t)z * n + i);
#pragma unroll
    for (int k = 0; k < 8; ++k) s[k] += (float)p[k];
  }
  half8 o = {(f16)s[0], (f16)s[1], (f16)s[2], (f16)s[3],
             (f16)s[4], (f16)s[5], (f16)s[6], (f16)s[7]};
  *(half8*)(out + i) = o;
}

// ---------------------------------------------------------------------------
// fused residual + f16 split-K slab reduce + (optional bias) + LayerNorm.
// ---------------------------------------------------------------------------
__global__ void add_ln(const float* __restrict__ a, const f16* __restrict__ b,
                       int nchunks, size_t cs, const float* __restrict__ bias,
                       const float* __restrict__ g, const float* __restrict__ be,
                       float* __restrict__ outf, f16* __restrict__ outh, int D) {
  const int row = blockIdx.x;
  const int t = threadIdx.x;
  const int lane = t & 63, wave = t >> 6;
  const float4 av = *(const float4*)(a + (size_t)row * D + t * 4);
  float s[4] = {av.x, av.y, av.z, av.w};
  for (int c = 0; c < nchunks; ++c) {
    const half4 bv = *(const half4*)(b + c * cs + (size_t)row * D + t * 4);
    s[0] += (float)bv[0]; s[1] += (float)bv[1];
    s[2] += (float)bv[2]; s[3] += (float)bv[3];
  }
  if (bias != nullptr) {
    const float4 bb = *(const float4*)(bias + t * 4);
    s[0] += bb.x; s[1] += bb.y; s[2] += bb.z; s[3] += bb.w;
  }
  float sum = s[0] + s[1] + s[2] + s[3];
  float sq = s[0] * s[0] + s[1] * s[1] + s[2] * s[2] + s[3] * s[3];
#pragma unroll
  for (int off = 32; off > 0; off >>= 1) {
    sum += __shfl_xor(sum, off);
    sq += __shfl_xor(sq, off);
  }
  __shared__ float red[8];
  if (lane == 0) {
    red[wave] = sum;
    red[4 + wave] = sq;
  }
  __syncthreads();
  sum = red[0] + red[1] + red[2] + red[3];
  sq = red[4] + red[5] + red[6] + red[7];
  const float mu = sum / (float)D;
  const float rv = rsqrtf(sq / (float)D - mu * mu + LN_EPS);
  const float4 gv = *(const float4*)(g + t * 4);
  const float4 bev = *(const float4*)(be + t * 4);
  float y0 = (s[0] - mu) * rv * gv.x + bev.x;
  float y1 = (s[1] - mu) * rv * gv.y + bev.y;
  float y2 = (s[2] - mu) * rv * gv.z + bev.z;
  float y3 = (s[3] - mu) * rv * gv.w + bev.w;
  if (outf != nullptr) {
    float4 o = {y0, y1, y2, y3};
    *(float4*)(outf + (size_t)row * D + t * 4) = o;
  }
  if (outh != nullptr) {
    f16* ob = outh + (size_t)row * D + t * 4;
    ob[0] = (f16)y0;
    ob[1] = (f16)y1;
    ob[2] = (f16)y2;
    ob[3] = (f16)y3;
  }
}

// ---------------------------------------------------------------------------
// launch
// ---------------------------------------------------------------------------
extern "C" void kernel_launch(void* const* d_in, const int* in_sizes, int n_in,
                              void* d_out, int out_size, void* d_ws,
                              size_t ws_size, hipStream_t stream) {
  constexpr int N = 4096, D = 1024, H = 4096;
  const float* x = (const float*)d_in[0];
  const float* Wq = (const float*)d_in[1];
  const float* Wk = (const float*)d_in[2];
  const float* Wv = (const float*)d_in[3];
  const float* Wo = (const float*)d_in[4];
  const float* W1 = (const float*)d_in[5];
  const float* b1 = (const float*)d_in[6];
  const float* W2 = (const float*)d_in[7];
  const float* b2 = (const float*)d_in[8];
  const float* g1 = (const float*)d_in[9];
  const float* be1 = (const float*)d_in[10];
  const float* g2 = (const float*)d_in[11];
  const float* be2 = (const float*)d_in[12];
  float* out = (float*)d_out;

  const size_t MB = 1024ull * 1024ull;
  char* w = (char*)d_ws;
  // workspace layout (hazard-checked reuse; offsets in MB):
  f16* xb   = (f16*)(w + 0 * MB);     // 8   [N,D]
  f16* Wqb  = (f16*)(w + 8 * MB);     // 8   [D,H]
  f16* Wkb  = (f16*)(w + 16 * MB);    // 8   [D,H]
  f16* Wvb  = (f16*)(w + 24 * MB);    // 8   [D,H]
  f16* WoT  = (f16*)(w + 32 * MB);    // 8   [D,H]
  f16* W1T  = (f16*)(w + 40 * MB);    // 8   [H,D]
  f16* W2T  = (f16*)(w + 48 * MB);    // 8   [D,H]
  f16* WqkT = (f16*)(w + 56 * MB);    // 2   [D,D]
  f16* WvoT = (f16*)(w + 58 * MB);    // 2   [D,D]
  f16* th   = (f16*)(w + 60 * MB);    // 8   [N,D]; dead after S
  f16* xvoT = (f16*)(w + 68 * MB);    // 8   [D,N]
  f16* F1   = (f16*)(w + 76 * MB);    // 32  [N,H]
  f16* Sh   = (f16*)(w + 108 * MB);   // 32  [N,N] f16; alive through PV
  f16* parA = (f16*)(w + 140 * MB);   // 32 = 4x8MB f16 slabs (old Pb slot)
  float* hf = (float*)(w + 172 * MB); // 16  [N,D]
  f16* hb   = (f16*)(w + 188 * MB);   // 8   [N,D]
  f16* parQK = (f16*)(w + 196 * MB);  // 16; dead after reduce_dual
  f16* parVO = (f16*)(w + 212 * MB);  // 16; dead after reduce_dual
  float* Smax = (float*)(w + 196 * MB);    // 1 MB [N][64] (over dead parQK)
  float* Ssum = (float*)(w + 197 * MB);    // 1 MB
  float2* rowstat = (float2*)(w + 198 * MB);  // 32 KB

  // ---- input prep ----
  prep_inputs<<<dim3(1024, 7), 256, 0, stream>>>(
      x, Wq, Wk, Wv, W1, Wo, W2, xb, Wqb, Wkb, Wvb, W1T, WoT, W2T);

  // ---- weight precomposition ----
  gemm_pre256<<<dim3(4, 4, 16), 512, 0, stream>>>(
      Wkb, Wqb, WoT, Wvb, parQK, parVO, D, H);
  reduce_dual<<<2 * (D * D) / 2048, 256, 0, stream>>>(parQK, parVO, WqkT,
                                                      WvoT, D * D);

  // ---- attention ----
  gemm_dual256<<<dim3(4, 32), 512, 0, stream>>>(xb, WqkT, WvoT, th, xvoT,
                                                N, D);
  // S = th @ xb^T [N,N] f16 logits + per-chunk softmax partial stats
  gemm_nt256<3><<<dim3(N / 256, N / 256, 1), 512, 0, stream>>>(
      th, xb, Sh, nullptr, Smax, Ssum, N, N, D, D, D, N);
  smax_reduce<<<N / 4, 256, 0, stream>>>(Smax, Ssum, rowstat);
  // attn partials = softmax(S) @ xvoT^T [N,D], split-K=4, exp fused in stage
  gemm_pv256<<<dim3(D / 256, N / 256, 4), 512, 0, stream>>>(
      Sh, xvoT, parA, rowstat, N, D, N, N, N, D);
  // h = LN(x + sum(attn partials))
  add_ln<<<N, 256, 0, stream>>>(x, parA, 4, (size_t)N * D, nullptr, g1, be1,
                                hf, hb, D);

  // ---- feed-forward ----
  gemm_nt256<2><<<dim3(H / 256, N / 256, 1), 512, 0, stream>>>(
      hb, W1T, F1, b1, nullptr, nullptr, N, H, D, D, D, H);
  gemm_nt256<1><<<dim3(D / 256, N / 256, 4), 512, 0, stream>>>(
      F1, W2T, parA, nullptr, nullptr, nullptr, N, D, H, H, H, D);
  add_ln<<<N, 256, 0, stream>>>(hf, parA, 4, (size_t)N * D, b2, g2, be2,
                                out, nullptr, D);
}

// Round 6
// 439.606 us; speedup vs baseline: 1.1170x; 1.1170x over previous
//
#include <hip/hip_runtime.h>
#include <hip/hip_bf16.h>

using f16 = _Float16;
typedef __attribute__((ext_vector_type(8))) f16 half8;
typedef __attribute__((ext_vector_type(4))) f16 half4;
typedef __attribute__((ext_vector_type(4))) float floatx4;

#define LN_EPS 1e-5f

// ---------------------------------------------------------------------------
// async global->LDS, 16B per lane. LDS dest is wave-uniform base + lane*16.
// ---------------------------------------------------------------------------
__device__ __forceinline__ void gload_lds16(const f16* g, f16* l) {
  __builtin_amdgcn_global_load_lds(
      (const __attribute__((address_space(1))) void*)g,
      (__attribute__((address_space(3))) void*)l, 16, 0, 0);
}

#define CFENCE asm volatile("" ::: "memory")
#define WAIT_VM(N) asm volatile("s_waitcnt vmcnt(" #N ")" ::: "memory")
#define BARRIER()                    \
  do {                               \
    CFENCE;                          \
    __builtin_amdgcn_s_barrier();    \
    CFENCE;                          \
  } while (0)

// ---------------------------------------------------------------------------
// 256x256-tile 8-phase pipelined GEMM core (T1+T2+T3+T4+T5), 512 thr
// (8 waves, 2Mx4N), BK=64, per-wave output 128x64 (acc[8][4] f32x4),
// 128 KiB LDS (2 K-tile buffers x (A 256x64 + B 256x64) f16).
// Schedule identical to the round-1 harness-verified kernel.
// EPI: 1 = f16 store; 2 = bias+relu;
//      3 = Punorm store: C = exp(v - m_chunk256) + stats Smax/Ssum[N][16]
//          (epilogue-only addition; main loop untouched).
// ---------------------------------------------------------------------------
template <int EPI>
__device__ __forceinline__ void gemm256_core(
    const f16* __restrict__ A, const f16* __restrict__ B,
    f16* __restrict__ Cz, const float* __restrict__ bias,
    int lda, int ldb, int ldc, int kper, int kbeg, int bm, int bn,
    f16* smp, float* __restrict__ Smax, float* __restrict__ Ssum) {
  const int t = threadIdx.x;
  const int wave = t >> 6, lane = t & 63;
  const int wm = (wave >> 2) << 7;  // wave M offset: 0/128
  const int wn = (wave & 3) << 6;   // wave N offset: 0/64/128/192
  const int lrow = lane & 15, lkc = lane >> 4;

  const int srow = lane >> 3;
  const int schunk = ((lane & 7) ^ srow) << 3;  // swizzled source chunk (elems)
  const f16* Ag = A + (size_t)(bm + wave * 16 + srow) * lda + kbeg + schunk;
  const f16* Bg = B + (size_t)(bn + wave * 16 + srow) * ldb + kbeg + schunk;

  const int co0 = ((lkc ^ (lrow & 7)) << 3);
  const int co1 = (((4 + lkc) ^ (lrow & 7)) << 3);

  floatx4 acc[8][4] = {};
  half8 af[4][2];
  half8 bf[2][2][2];

  auto STAGE = [&](int b, int tt, int h) {  // h: 0=A-lo 1=A-hi 2=B-lo 3=B-hi
    if (h < 2) {
      const f16* src = Ag + (size_t)(h * 128) * lda + tt * 64;
      f16* d = smp + (b * 2) * 16384 + h * 8192 + wave * 1024;
      gload_lds16(src, d);
      gload_lds16(src + (size_t)8 * lda, d + 512);
    } else {
      const f16* src = Bg + (size_t)((h - 2) * 128) * ldb + tt * 64;
      f16* d = smp + (b * 2 + 1) * 16384 + (h - 2) * 8192 + wave * 1024;
      gload_lds16(src, d);
      gload_lds16(src + (size_t)8 * ldb, d + 512);
    }
  };
  auto LDA = [&](int b, int qm) {
    const f16* base = smp + (b * 2) * 16384 + (wm + qm * 64 + lrow) * 64;
#pragma unroll
    for (int fm = 0; fm < 4; ++fm) {
      af[fm][0] = *(const half8*)(base + fm * (16 * 64) + co0);
      af[fm][1] = *(const half8*)(base + fm * (16 * 64) + co1);
    }
  };
  auto LDB = [&](int b, int qn) {
    const f16* base = smp + (b * 2 + 1) * 16384 + (wn + qn * 32 + lrow) * 64;
#pragma unroll
    for (int fn = 0; fn < 2; ++fn) {
      bf[qn][fn][0] = *(const half8*)(base + fn * (16 * 64) + co0);
      bf[qn][fn][1] = *(const half8*)(base + fn * (16 * 64) + co1);
    }
  };
  auto MFMAQ = [&](int qm, int qn) {
    __builtin_amdgcn_s_setprio(1);
#pragma unroll
    for (int kk = 0; kk < 2; ++kk)
#pragma unroll
      for (int fm = 0; fm < 4; ++fm)
#pragma unroll
        for (int fn = 0; fn < 2; ++fn)
          acc[qm * 4 + fm][qn * 2 + fn] =
              __builtin_amdgcn_mfma_f32_16x16x32_f16(
                  af[fm][kk], bf[qn][fn][kk], acc[qm * 4 + fm][qn * 2 + fn],
                  0, 0, 0);
    __builtin_amdgcn_s_setprio(0);
  };

  const int NT = kper >> 6;
  const int NI = NT >> 1;

  STAGE(0, 0, 0); STAGE(0, 0, 1); STAGE(0, 0, 2); STAGE(0, 0, 3);
  STAGE(1, 1, 0);
  WAIT_VM(2);
  BARRIER();

  for (int i = 0; i < NI; ++i) {
    const bool last = (i == NI - 1);
    const int tb = 2 * i;
    // P0
    LDA(0, 0); LDB(0, 0); STAGE(1, tb + 1, 1);
    BARRIER(); MFMAQ(0, 0); BARRIER();
    // P1
    LDB(0, 1); STAGE(1, tb + 1, 2);
    BARRIER(); MFMAQ(0, 1); BARRIER();
    // P2
    LDA(0, 1); STAGE(1, tb + 1, 3);
    BARRIER(); MFMAQ(1, 0); BARRIER();
    // P3
    if (!last) {
      STAGE(0, tb + 2, 0);
      WAIT_VM(2);
    } else {
      WAIT_VM(0);
    }
    BARRIER(); MFMAQ(1, 1); BARRIER();
    // P4
    LDA(1, 0); LDB(1, 0);
    if (!last) STAGE(0, tb + 2, 1);
    BARRIER(); MFMAQ(0, 0); BARRIER();
    // P5
    LDB(1, 1);
    if (!last) STAGE(0, tb + 2, 2);
    BARRIER(); MFMAQ(0, 1); BARRIER();
    // P6
    LDA(1, 1);
    if (!last) STAGE(0, tb + 2, 3);
    BARRIER(); MFMAQ(1, 0); BARRIER();
    // P7
    if (!last) {
      STAGE(1, tb + 3, 0);
      WAIT_VM(2);
    }
    BARRIER(); MFMAQ(1, 1); BARRIER();
  }

  // epilogue: C/D col = lane&15, row = (lane>>4)*4 + reg
  const int crow0 = bm + wm + lkc * 4;
  const int ccol0 = bn + wn + lrow;
  if (EPI == 3) {
    // sm is dead after the trailing barrier; reuse first 8 KB for stats.
    float* mt = (float*)smp;          // [8 waves][128 rows] chunk-64 max
    float* st = ((float*)smp) + 1024; // [8 waves][128 rows] chunk-64 expsum
    const int wm2 = wave >> 2, wvc = wave & 3;
    const int rb_ = lkc * 4;
    float m256[8][4];
#pragma unroll
    for (int i = 0; i < 8; ++i)
#pragma unroll
      for (int r2 = 0; r2 < 4; ++r2) {
        float mx = fmaxf(fmaxf(acc[i][0][r2], acc[i][1][r2]),
                         fmaxf(acc[i][2][r2], acc[i][3][r2]));
#pragma unroll
        for (int m_ = 8; m_ >= 1; m_ >>= 1)
          mx = fmaxf(mx, __shfl_xor(mx, m_));
        if (lrow == 0) mt[wave * 128 + rb_ + i * 16 + r2] = mx;
      }
    __syncthreads();
#pragma unroll
    for (int i = 0; i < 8; ++i)
#pragma unroll
      for (int r2 = 0; r2 < 4; ++r2) {
        const int rl = rb_ + i * 16 + r2;
        m256[i][r2] = fmaxf(
            fmaxf(mt[(wm2 * 4 + 0) * 128 + rl], mt[(wm2 * 4 + 1) * 128 + rl]),
            fmaxf(mt[(wm2 * 4 + 2) * 128 + rl], mt[(wm2 * 4 + 3) * 128 + rl]));
      }
#pragma unroll
    for (int i = 0; i < 8; ++i)
#pragma unroll
      for (int r2 = 0; r2 < 4; ++r2) {
        float s = 0.0f;
#pragma unroll
        for (int j = 0; j < 4; ++j)
          s += __expf(acc[i][j][r2] - m256[i][r2]);
#pragma unroll
        for (int m_ = 8; m_ >= 1; m_ >>= 1) s += __shfl_xor(s, m_);
        if (lrow == 0) st[wave * 128 + rb_ + i * 16 + r2] = s;
      }
    __syncthreads();
    if (wvc == 0 && lrow == 0) {
      const int chunk = bn >> 8;
#pragma unroll
      for (int i = 0; i < 8; ++i)
#pragma unroll
        for (int r2 = 0; r2 < 4; ++r2) {
          const int rl = rb_ + i * 16 + r2;
          const int row = crow0 + i * 16 + r2;
          const float ss = st[(wm2 * 4 + 0) * 128 + rl] +
                           st[(wm2 * 4 + 1) * 128 + rl] +
                           st[(wm2 * 4 + 2) * 128 + rl] +
                           st[(wm2 * 4 + 3) * 128 + rl];
          Smax[(size_t)row * 16 + chunk] = m256[i][r2];
          Ssum[(size_t)row * 16 + chunk] = ss;
        }
    }
#pragma unroll
    for (int i = 0; i < 8; ++i)
#pragma unroll
      for (int r2 = 0; r2 < 4; ++r2) {
        const size_t row = (size_t)(crow0 + i * 16 + r2);
#pragma unroll
        for (int j = 0; j < 4; ++j)
          Cz[row * (size_t)ldc + ccol0 + j * 16] =
              (f16)__expf(acc[i][j][r2] - m256[i][r2]);
      }
  } else {
#pragma unroll
    for (int i = 0; i < 8; ++i) {
#pragma unroll
      for (int r2 = 0; r2 < 4; ++r2) {
        const size_t row = (size_t)(crow0 + i * 16 + r2);
#pragma unroll
        for (int j = 0; j < 4; ++j) {
          const int col = ccol0 + j * 16;
          float v = acc[i][j][r2];
          if (EPI == 2) v = fmaxf(v + bias[col], 0.0f);
          Cz[row * (size_t)ldc + col] = (f16)v;
        }
      }
    }
  }
}

// bijective XCD-chunked swizzle (T1).
__device__ __forceinline__ int xcd_swizzle(int id, int nwg) {
  const int q = nwg >> 3, r = nwg & 7;
  const int xcd = id & 7, lin = id >> 3;
  return (xcd < r ? xcd * (q + 1) : r * (q + 1) + (xcd - r) * q) + lin;
}

// ---------------------------------------------------------------------------
// generic NT wrapper: C = A*B^T, split-K via gridDim.z.
// ---------------------------------------------------------------------------
template <int EPI>
__global__ __launch_bounds__(512, 2) void gemm_nt256(
    const f16* __restrict__ A, const f16* __restrict__ B,
    f16* __restrict__ Ch, const float* __restrict__ bias,
    float* __restrict__ Smax, float* __restrict__ Ssum,
    int M, int Nc, int K, int lda, int ldb, int ldc) {
  __shared__ f16 sm[4][256 * 64];
  const int gx = gridDim.x, gy = gridDim.y;
  const int nwg = gx * gy * gridDim.z;
  const int id = blockIdx.x + gx * (blockIdx.y + gy * blockIdx.z);
  const int nid = xcd_swizzle(id, nwg);
  const int bx = nid % gx;
  const int by = (nid / gx) % gy;
  const int bz = nid / (gx * gy);
  const int kper = K / gridDim.z;
  gemm256_core<EPI>(A, B, Ch + (size_t)bz * M * ldc, bias, lda, ldb, ldc,
                    kper, bz * kper, by << 8, bx << 8, &sm[0][0], Smax, Ssum);
}

// ---------------------------------------------------------------------------
// weight precompose on the 8-phase core: grid (4,4,16).
// ---------------------------------------------------------------------------
__global__ __launch_bounds__(512, 2) void gemm_pre256(
    const f16* __restrict__ Wkb, const f16* __restrict__ Wqb,
    const f16* __restrict__ WoT, const f16* __restrict__ Wvb,
    f16* __restrict__ parQK, f16* __restrict__ parVO, int D, int H) {
  __shared__ f16 sm[4][256 * 64];
  const int id = blockIdx.x + 4 * (blockIdx.y + 4 * blockIdx.z);
  const int nid = xcd_swizzle(id, 256);
  const int bx = nid & 3, by = (nid >> 2) & 3, z = nid >> 4;
  const int zz = z & 7;
  const f16* A = (z < 8) ? Wkb : WoT;
  const f16* B = (z < 8) ? Wqb : Wvb;
  f16* slab = ((z < 8) ? parQK : parVO) + (size_t)zz * D * D;
  gemm256_core<1>(A, B, slab, nullptr, H, H, D, H / 8, zz * (H / 8),
                  by << 8, bx << 8, &sm[0][0], nullptr, nullptr);
}

// ---------------------------------------------------------------------------
// merged th/xvoT on the 8-phase core: grid (4,32).
// ---------------------------------------------------------------------------
__global__ __launch_bounds__(512, 2) void gemm_dual256(
    const f16* __restrict__ xb, const f16* __restrict__ WqkT,
    const f16* __restrict__ WvoT, f16* __restrict__ th,
    f16* __restrict__ xvoT, int N, int D) {
  __shared__ f16 sm[4][256 * 64];
  const int id = blockIdx.x + 4 * blockIdx.y;
  const int nid = xcd_swizzle(id, 128);
  const int bx = nid & 3, y = nid >> 2;
  if (y < 16)
    gemm256_core<1>(xb, WqkT, th, nullptr, D, D, D, D, 0,
                    y << 8, bx << 8, &sm[0][0], nullptr, nullptr);
  else
    gemm256_core<1>(WvoT, xb, xvoT, nullptr, D, D, N, D, 0,
                    bx << 8, (y - 16) << 8, &sm[0][0], nullptr, nullptr);
}

// ---------------------------------------------------------------------------
// PV GEMM: attn-slab_z = (online-rescaled Punorm) @ xvoT^T. Staging schedule
// is BYTE-IDENTICAL to gemm256_core (A = Punorm f16 via global_load_lds).
// Additions are pure VALU/LDS, outside the staging/wait stream:
//  - prologue: preload Tfac[bm..bm+255][4z..4z+3] -> tf LDS (drained before
//    staging, so vmcnt counts unchanged)
//  - acc *= tf[row][tix] at chunk transitions (loop i = 2,4,6)
//  - epilogue: acc *= tf[row][0] (exp(m_last - m_row) * inv_row)
// ---------------------------------------------------------------------------
__global__ __launch_bounds__(512, 2) void gemm_pv256(
    const f16* __restrict__ A, const f16* __restrict__ B,
    f16* __restrict__ Ch, const float* __restrict__ Tfac,
    int M, int Nc, int K, int lda, int ldb, int ldc) {
  __shared__ f16 sm[4][256 * 64];
  __shared__ float tf[256 * 4];
  f16* smp = &sm[0][0];
  const int gx = gridDim.x, gy = gridDim.y;
  const int nwg = gx * gy * gridDim.z;
  const int id = blockIdx.x + gx * (blockIdx.y + gy * blockIdx.z);
  const int nid = xcd_swizzle(id, nwg);
  const int bx = nid % gx;
  const int by = (nid / gx) % gy;
  const int bz = nid / (gx * gy);
  const int kper = K / gridDim.z;
  const int kbeg = bz * kper;
  f16* Cz = Ch + (size_t)bz * M * ldc;
  const int bm = by << 8, bn = bx << 8;

  const int t = threadIdx.x;
  const int wave = t >> 6, lane = t & 63;
  const int wm = (wave >> 2) << 7;
  const int wn = (wave & 3) << 6;
  const int lrow = lane & 15, lkc = lane >> 4;
  const int srow = lane >> 3;
  const int schunk = ((lane & 7) ^ srow) << 3;
  const f16* Ag = A + (size_t)(bm + wave * 16 + srow) * lda + kbeg + schunk;
  const f16* Bg = B + (size_t)(bn + wave * 16 + srow) * ldb + kbeg + schunk;
  const int co0 = ((lkc ^ (lrow & 7)) << 3);
  const int co1 = (((4 + lkc) ^ (lrow & 7)) << 3);

  floatx4 acc[8][4] = {};
  half8 af[4][2];
  half8 bf[2][2][2];

  auto STAGE = [&](int b, int tt, int h) {
    if (h < 2) {
      const f16* src = Ag + (size_t)(h * 128) * lda + tt * 64;
      f16* d = smp + (b * 2) * 16384 + h * 8192 + wave * 1024;
      gload_lds16(src, d);
      gload_lds16(src + (size_t)8 * lda, d + 512);
    } else {
      const f16* src = Bg + (size_t)((h - 2) * 128) * ldb + tt * 64;
      f16* d = smp + (b * 2 + 1) * 16384 + (h - 2) * 8192 + wave * 1024;
      gload_lds16(src, d);
      gload_lds16(src + (size_t)8 * ldb, d + 512);
    }
  };
  auto LDA = [&](int b, int qm) {
    const f16* base = smp + (b * 2) * 16384 + (wm + qm * 64 + lrow) * 64;
#pragma unroll
    for (int fm = 0; fm < 4; ++fm) {
      af[fm][0] = *(const half8*)(base + fm * (16 * 64) + co0);
      af[fm][1] = *(const half8*)(base + fm * (16 * 64) + co1);
    }
  };
  auto LDB = [&](int b, int qn) {
    const f16* base = smp + (b * 2 + 1) * 16384 + (wn + qn * 32 + lrow) * 64;
#pragma unroll
    for (int fn = 0; fn < 2; ++fn) {
      bf[qn][fn][0] = *(const half8*)(base + fn * (16 * 64) + co0);
      bf[qn][fn][1] = *(const half8*)(base + fn * (16 * 64) + co1);
    }
  };
  auto MFMAQ = [&](int qm, int qn) {
    __builtin_amdgcn_s_setprio(1);
#pragma unroll
    for (int kk = 0; kk < 2; ++kk)
#pragma unroll
      for (int fm = 0; fm < 4; ++fm)
#pragma unroll
        for (int fn = 0; fn < 2; ++fn)
          acc[qm * 4 + fm][qn * 2 + fn] =
              __builtin_amdgcn_mfma_f32_16x16x32_f16(
                  af[fm][kk], bf[qn][fn][kk], acc[qm * 4 + fm][qn * 2 + fn],
                  0, 0, 0);
    __builtin_amdgcn_s_setprio(0);
  };

  // preload factor table BEFORE any staging (loads fully drained by the
  // compiler-inserted wait for the ds_write data dependency).
  {
    const int r = t >> 1, p = (t & 1) * 2;
    const float2 tv =
        *(const float2*)(Tfac + (size_t)(bm + r) * 16 + bz * 4 + p);
    tf[r * 4 + p] = tv.x;
    tf[r * 4 + p + 1] = tv.y;
    asm volatile("s_waitcnt lgkmcnt(0)" ::: "memory");
  }

  const int NT = kper >> 6;  // = 16 here
  const int NI = NT >> 1;    // = 8

  STAGE(0, 0, 0); STAGE(0, 0, 1); STAGE(0, 0, 2); STAGE(0, 0, 3);
  STAGE(1, 1, 0);
  WAIT_VM(2);
  BARRIER();

  for (int i = 0; i < NI; ++i) {
    const bool last = (i == NI - 1);
    const int tb = 2 * i;
    // P0 (+ chunk-transition rescale: pure VALU/LDS, pre-barrier)
    LDA(0, 0); LDB(0, 0); STAGE(1, tb + 1, 1);
    if (i > 0 && (i & 1) == 0) {
      const int tix = i >> 1;  // 1,2,3
#pragma unroll
      for (int i16 = 0; i16 < 8; ++i16)
#pragma unroll
        for (int r2 = 0; r2 < 4; ++r2) {
          const float f = tf[(wm + lkc * 4 + i16 * 16 + r2) * 4 + tix];
#pragma unroll
          for (int j = 0; j < 4; ++j) acc[i16][j][r2] *= f;
        }
    }
    BARRIER(); MFMAQ(0, 0); BARRIER();
    // P1
    LDB(0, 1); STAGE(1, tb + 1, 2);
    BARRIER(); MFMAQ(0, 1); BARRIER();
    // P2
    LDA(0, 1); STAGE(1, tb + 1, 3);
    BARRIER(); MFMAQ(1, 0); BARRIER();
    // P3
    if (!last) {
      STAGE(0, tb + 2, 0);
      WAIT_VM(2);
    } else {
      WAIT_VM(0);
    }
    BARRIER(); MFMAQ(1, 1); BARRIER();
    // P4
    LDA(1, 0); LDB(1, 0);
    if (!last) STAGE(0, tb + 2, 1);
    BARRIER(); MFMAQ(0, 0); BARRIER();
    // P5
    LDB(1, 1);
    if (!last) STAGE(0, tb + 2, 2);
    BARRIER(); MFMAQ(0, 1); BARRIER();
    // P6
    LDA(1, 1);
    if (!last) STAGE(0, tb + 2, 3);
    BARRIER(); MFMAQ(1, 0); BARRIER();
    // P7
    if (!last) {
      STAGE(1, tb + 3, 0);
      WAIT_VM(2);
    }
    BARRIER(); MFMAQ(1, 1); BARRIER();
  }

  // epilogue: final frame -> exp(m_last - m_row) * inv_row, then store
  const int crow0 = bm + wm + lkc * 4;
  const int ccol0 = bn + wn + lrow;
#pragma unroll
  for (int i = 0; i < 8; ++i) {
#pragma unroll
    for (int r2 = 0; r2 < 4; ++r2) {
      const float f = tf[(wm + lkc * 4 + i * 16 + r2) * 4];
      const size_t row = (size_t)(crow0 + i * 16 + r2);
#pragma unroll
      for (int j = 0; j < 4; ++j)
        Cz[row * (size_t)ldc + ccol0 + j * 16] = (f16)(acc[i][j][r2] * f);
    }
  }
}

// ---------------------------------------------------------------------------
// combine per-chunk stats -> factor table. 16 chunks/row. Per row:
// m_row = max_c m_c; s_row = sum_c s_c*exp(m_c - m_row); inv = 1/s_row.
// Tfac[row][c]: c%4==0 -> exp(m_{c+3} - m_row)*inv (final factor for z=c/4)
//               c%4>0  -> exp(m_{c-1} - m_c)       (transition factor)
// grid N/16, block 256 (16 rows/block, 16 lanes/row).
// ---------------------------------------------------------------------------
__global__ void smax_reduce2(const float* __restrict__ Smax,
                             const float* __restrict__ Ssum,
                             float* __restrict__ Tfac) {
  const int t = threadIdx.x;
  const int row = blockIdx.x * 16 + (t >> 4);
  const int c = t & 15;
  const int lane = t & 63;
  const float mc = Smax[(size_t)row * 16 + c];
  const float sc = Ssum[(size_t)row * 16 + c];
  float m = mc;
#pragma unroll
  for (int off = 8; off >= 1; off >>= 1) m = fmaxf(m, __shfl_xor(m, off));
  float s = sc * __expf(mc - m);
#pragma unroll
  for (int off = 8; off >= 1; off >>= 1) s += __shfl_xor(s, off);
  const float inv = 1.0f / s;
  const int base = lane & ~15;
  const float mprev = __shfl(mc, base | ((c - 1) & 15));
  const float mlast = __shfl(mc, base | (c | 3));
  float f;
  if ((c & 3) == 0)
    f = __expf(mlast - m) * inv;
  else
    f = __expf(mprev - mc);
  Tfac[(size_t)row * 16 + c] = f;
}

// ---------------------------------------------------------------------------
// fused input prep (round-3 verified variant), grid (1024, 7), block 256.
// ---------------------------------------------------------------------------
__global__ void prep_inputs(const float* x, const float* Wq, const float* Wk,
                            const float* Wv, const float* W1, const float* Wo,
                            const float* W2, f16* xb, f16* Wqb, f16* Wkb,
                            f16* Wvb, f16* W1T, f16* WoT, f16* W2T) {
  const int z = blockIdx.y;
  const int b = blockIdx.x;
  const int t = threadIdx.x;
  if (z >= 3) {
    const float* in = (z == 3) ? x : (z == 4) ? Wq : (z == 5) ? Wk : Wv;
    f16* out = (z == 3) ? xb : (z == 4) ? Wqb : (z == 5) ? Wkb : Wvb;
    const size_t i = ((size_t)b * 256 + t) * 16;
    const float4 a0 = *(const float4*)(in + i);
    const float4 a1 = *(const float4*)(in + i + 4);
    const float4 a2 = *(const float4*)(in + i + 8);
    const float4 a3 = *(const float4*)(in + i + 12);
    half8 v0 = {(f16)a0.x, (f16)a0.y, (f16)a0.z, (f16)a0.w,
                (f16)a1.x, (f16)a1.y, (f16)a1.z, (f16)a1.w};
    half8 v1 = {(f16)a2.x, (f16)a2.y, (f16)a2.z, (f16)a2.w,
                (f16)a3.x, (f16)a3.y, (f16)a3.z, (f16)a3.w};
    *(half8*)(out + i) = v0;
    *(half8*)(out + i + 8) = v1;
    return;
  }
  int R, C, tx, ty;
  const float* in;
  f16* out;
  if (z == 0) {
    R = 1024; C = 4096; in = W1; out = W1T;
    tx = b & 63; ty = b >> 6;
  } else {
    R = 4096; C = 1024; in = (z == 1) ? Wo : W2;
    out = (z == 1) ? WoT : W2T;
    tx = b & 15; ty = b >> 4;
  }
  const int r0 = ty << 6, c0 = tx << 6;
  __shared__ f16 lt[64 * 64];
  const int lr = t >> 4;
  const int lc = t & 15;
  const int q3 = lr & 3;
  const int rb = lr & ~3;
  const int myc = lc * 4 + q3;
#pragma unroll
  for (int rr = 0; rr < 4; ++rr) {
    const int r = lr + rr * 16;
    const float4 f = *(const float4*)(in + (size_t)(r0 + r) * C + c0 + lc * 4);
    float v0 = f.x, v1 = f.y, v2 = f.z, v3 = f.w;
    {
      const bool hi = (q3 & 2) != 0;
      float sA = hi ? v0 : v2;
      float sB = hi ? v1 : v3;
      sA = __shfl_xor(sA, 32);
      sB = __shfl_xor(sB, 32);
      if (hi) { v0 = sA; v1 = sB; } else { v2 = sA; v3 = sB; }
    }
    {
      const bool od = (q3 & 1) != 0;
      float sC = od ? v0 : v1;
      float sD = od ? v2 : v3;
      sC = __shfl_xor(sC, 16);
      sD = __shfl_xor(sD, 16);
      if (od) { v0 = sC; v2 = sD; } else { v1 = sC; v3 = sD; }
    }
    half4 hv = {(f16)v0, (f16)v1, (f16)v2, (f16)v3};
    const int rbase = rb + rr * 16;
    *(half4*)(lt + myc * 64 + (rbase ^ ((myc & 15) << 2))) = hv;
  }
  __syncthreads();
  const int oc = t >> 3, orr = (t & 7) << 3;
#pragma unroll
  for (int cc = 0; cc < 2; ++cc) {
    const int c = oc + cc * 32;
    const int swz = (c & 15) << 2;
    const half4 ha = *(const half4*)(lt + c * 64 + (orr ^ swz));
    const half4 hb4 = *(const half4*)(lt + c * 64 + ((orr + 4) ^ swz));
    half8 v = {ha[0], ha[1], ha[2], ha[3], hb4[0], hb4[1], hb4[2], hb4[3]};
    *(half8*)(out + (size_t)(c0 + c) * R + r0 + orr) = v;
  }
}

// ---------------------------------------------------------------------------
// merged slab reduce: 16B/lane loads.
// ---------------------------------------------------------------------------
__global__ void reduce_dual(const f16* __restrict__ parQK,
                            const f16* __restrict__ parVO,
                            f16* __restrict__ WqkT, f16* __restrict__ WvoT,
                            int n) {
  const int half = gridDim.x >> 1;
  const bool second = blockIdx.x >= half;
  const f16* par = second ? parVO : parQK;
  f16* out = second ? WvoT : WqkT;
  const int b = second ? blockIdx.x - half : blockIdx.x;
  const int i = (b * 256 + threadIdx.x) * 8;
  float s[8] = {};
#pragma unroll
  for (int z = 0; z < 8; ++z) {
    const half8 p = *(const half8*)(par + (size_t)z * n + i);
#pragma unroll
    for (int k = 0; k < 8; ++k) s[k] += (float)p[k];
  }
  half8 o = {(f16)s[0], (f16)s[1], (f16)s[2], (f16)s[3],
             (f16)s[4], (f16)s[5], (f16)s[6], (f16)s[7]};
  *(half8*)(out + i) = o;
}

// ---------------------------------------------------------------------------
// fused residual + f16 split-K slab reduce + (optional bias) + LayerNorm.
// ---------------------------------------------------------------------------
__global__ void add_ln(const float* __restrict__ a, const f16* __restrict__ b,
                       int nchunks, size_t cs, const float* __restrict__ bias,
                       const float* __restrict__ g, const float* __restrict__ be,
                       float* __restrict__ outf, f16* __restrict__ outh, int D) {
  const int row = blockIdx.x;
  const int t = threadIdx.x;
  const int lane = t & 63, wave = t >> 6;
  const float4 av = *(const float4*)(a + (size_t)row * D + t * 4);
  float s[4] = {av.x, av.y, av.z, av.w};
  for (int c = 0; c < nchunks; ++c) {
    const half4 bv = *(const half4*)(b + c * cs + (size_t)row * D + t * 4);
    s[0] += (float)bv[0]; s[1] += (float)bv[1];
    s[2] += (float)bv[2]; s[3] += (float)bv[3];
  }
  if (bias != nullptr) {
    const float4 bb = *(const float4*)(bias + t * 4);
    s[0] += bb.x; s[1] += bb.y; s[2] += bb.z; s[3] += bb.w;
  }
  float sum = s[0] + s[1] + s[2] + s[3];
  float sq = s[0] * s[0] + s[1] * s[1] + s[2] * s[2] + s[3] * s[3];
#pragma unroll
  for (int off = 32; off > 0; off >>= 1) {
    sum += __shfl_xor(sum, off);
    sq += __shfl_xor(sq, off);
  }
  __shared__ float red[8];
  if (lane == 0) {
    red[wave] = sum;
    red[4 + wave] = sq;
  }
  __syncthreads();
  sum = red[0] + red[1] + red[2] + red[3];
  sq = red[4] + red[5] + red[6] + red[7];
  const float mu = sum / (float)D;
  const float rv = rsqrtf(sq / (float)D - mu * mu + LN_EPS);
  const float4 gv = *(const float4*)(g + t * 4);
  const float4 bev = *(const float4*)(be + t * 4);
  float y0 = (s[0] - mu) * rv * gv.x + bev.x;
  float y1 = (s[1] - mu) * rv * gv.y + bev.y;
  float y2 = (s[2] - mu) * rv * gv.z + bev.z;
  float y3 = (s[3] - mu) * rv * gv.w + bev.w;
  if (outf != nullptr) {
    float4 o = {y0, y1, y2, y3};
    *(float4*)(outf + (size_t)row * D + t * 4) = o;
  }
  if (outh != nullptr) {
    f16* ob = outh + (size_t)row * D + t * 4;
    ob[0] = (f16)y0;
    ob[1] = (f16)y1;
    ob[2] = (f16)y2;
    ob[3] = (f16)y3;
  }
}

// ---------------------------------------------------------------------------
// launch
// ---------------------------------------------------------------------------
extern "C" void kernel_launch(void* const* d_in, const int* in_sizes, int n_in,
                              void* d_out, int out_size, void* d_ws,
                              size_t ws_size, hipStream_t stream) {
  constexpr int N = 4096, D = 1024, H = 4096;
  const float* x = (const float*)d_in[0];
  const float* Wq = (const float*)d_in[1];
  const float* Wk = (const float*)d_in[2];
  const float* Wv = (const float*)d_in[3];
  const float* Wo = (const float*)d_in[4];
  const float* W1 = (const float*)d_in[5];
  const float* b1 = (const float*)d_in[6];
  const float* W2 = (const float*)d_in[7];
  const float* b2 = (const float*)d_in[8];
  const float* g1 = (const float*)d_in[9];
  const float* be1 = (const float*)d_in[10];
  const float* g2 = (const float*)d_in[11];
  const float* be2 = (const float*)d_in[12];
  float* out = (float*)d_out;

  const size_t MB = 1024ull * 1024ull;
  char* w = (char*)d_ws;
  // workspace layout (hazard-checked reuse; offsets in MB):
  f16* xb   = (f16*)(w + 0 * MB);     // 8   [N,D]
  f16* Wqb  = (f16*)(w + 8 * MB);     // 8   [D,H]
  f16* Wkb  = (f16*)(w + 16 * MB);    // 8   [D,H]
  f16* Wvb  = (f16*)(w + 24 * MB);    // 8   [D,H]
  f16* WoT  = (f16*)(w + 32 * MB);    // 8   [D,H]
  f16* W1T  = (f16*)(w + 40 * MB);    // 8   [H,D]
  f16* W2T  = (f16*)(w + 48 * MB);    // 8   [D,H]
  f16* WqkT = (f16*)(w + 56 * MB);    // 2   [D,D]
  f16* WvoT = (f16*)(w + 58 * MB);    // 2   [D,D]
  f16* th   = (f16*)(w + 60 * MB);    // 8   [N,D]; dead after S
  f16* xvoT = (f16*)(w + 68 * MB);    // 8   [D,N]
  f16* F1   = (f16*)(w + 76 * MB);    // 32  [N,H]
  f16* Sh   = (f16*)(w + 108 * MB);   // 32  [N,N] Punorm; alive through PV
  f16* parA = (f16*)(w + 140 * MB);   // 32 = 4x8MB f16 slabs
  float* hf = (float*)(w + 172 * MB); // 16  [N,D]
  f16* hb   = (f16*)(w + 188 * MB);   // 8   [N,D]
  f16* parQK = (f16*)(w + 196 * MB);  // 16; dead after reduce_dual
  f16* parVO = (f16*)(w + 212 * MB);  // 16; dead after reduce_dual
  float* Smax = (float*)(w + 196 * MB);  // 256 KB [N][16] (over dead parQK)
  float* Ssum = (float*)(w + 197 * MB);  // 256 KB
  float* Tfac = (float*)(w + 198 * MB);  // 256 KB [N][16]

  // ---- input prep ----
  prep_inputs<<<dim3(1024, 7), 256, 0, stream>>>(
      x, Wq, Wk, Wv, W1, Wo, W2, xb, Wqb, Wkb, Wvb, W1T, WoT, W2T);

  // ---- weight precomposition ----
  gemm_pre256<<<dim3(4, 4, 16), 512, 0, stream>>>(
      Wkb, Wqb, WoT, Wvb, parQK, parVO, D, H);
  reduce_dual<<<2 * (D * D) / 2048, 256, 0, stream>>>(parQK, parVO, WqkT,
                                                      WvoT, D * D);

  // ---- attention ----
  gemm_dual256<<<dim3(4, 32), 512, 0, stream>>>(xb, WqkT, WvoT, th, xvoT,
                                                N, D);
  // Sh = exp(th@xb^T - m_chunk256) + stats, one pass
  gemm_nt256<3><<<dim3(N / 256, N / 256, 1), 512, 0, stream>>>(
      th, xb, Sh, nullptr, Smax, Ssum, N, N, D, D, D, N);
  smax_reduce2<<<N / 16, 256, 0, stream>>>(Smax, Ssum, Tfac);
  // attn partials, split-K=4, online-rescaled accumulator
  gemm_pv256<<<dim3(D / 256, N / 256, 4), 512, 0, stream>>>(
      Sh, xvoT, parA, Tfac, N, D, N, N, N, D);
  // h = LN(x + sum(attn partials))
  add_ln<<<N, 256, 0, stream>>>(x, parA, 4, (size_t)N * D, nullptr, g1, be1,
                                hf, hb, D);

  // ---- feed-forward ----
  gemm_nt256<2><<<dim3(H / 256, N / 256, 1), 512, 0, stream>>>(
      hb, W1T, F1, b1, nullptr, nullptr, N, H, D, D, D, H);
  gemm_nt256<1><<<dim3(D / 256, N / 256, 4), 512, 0, stream>>>(
      F1, W2T, parA, nullptr, nullptr, nullptr, N, D, H, H, H, D);
  add_ln<<<N, 256, 0, stream>>>(hf, parA, 4, (size_t)N * D, b2, g2, be2,
                                out, nullptr, D);
}

// Round 7
// 413.632 us; speedup vs baseline: 1.1871x; 1.0628x over previous
//
#include <hip/hip_runtime.h>
#include <hip/hip_bf16.h>

using f16 = _Float16;
typedef __attribute__((ext_vector_type(8))) f16 half8;
typedef __attribute__((ext_vector_type(4))) f16 half4;
typedef __attribute__((ext_vector_type(4))) float floatx4;

#define LN_EPS 1e-5f

// ---------------------------------------------------------------------------
// async global->LDS, 16B per lane. LDS dest is wave-uniform base + lane*16.
// ---------------------------------------------------------------------------
__device__ __forceinline__ void gload_lds16(const f16* g, f16* l) {
  __builtin_amdgcn_global_load_lds(
      (const __attribute__((address_space(1))) void*)g,
      (__attribute__((address_space(3))) void*)l, 16, 0, 0);
}

#define CFENCE asm volatile("" ::: "memory")
#define WAIT_VM(N) asm volatile("s_waitcnt vmcnt(" #N ")" ::: "memory")
#define BARRIER()                    \
  do {                               \
    CFENCE;                          \
    __builtin_amdgcn_s_barrier();    \
    CFENCE;                          \
  } while (0)

// ---------------------------------------------------------------------------
// 256x256-tile 8-phase pipelined GEMM core (T1+T2+T3+T4+T5), 512 thr
// (8 waves, 2Mx4N), BK=64, per-wave output 128x64 (acc[8][4] f32x4),
// 128 KiB LDS (2 K-tile buffers x (A 256x64 + B 256x64) f16).
// Schedule identical to the round-1 harness-verified kernel.
// ---------------------------------------------------------------------------
template <int EPI>
__device__ __forceinline__ void gemm256_core(
    const f16* __restrict__ A, const f16* __restrict__ B,
    f16* __restrict__ Cz, const float* __restrict__ bias,
    int lda, int ldb, int ldc, int kper, int kbeg, int bm, int bn,
    f16* smp) {
  const int t = threadIdx.x;
  const int wave = t >> 6, lane = t & 63;
  const int wm = (wave >> 2) << 7;  // wave M offset: 0/128
  const int wn = (wave & 3) << 6;   // wave N offset: 0/64/128/192
  const int lrow = lane & 15, lkc = lane >> 4;

  // staging: seg = wave*2+l covers 8 rows of a 128-row half-tile
  const int srow = lane >> 3;
  const int schunk = ((lane & 7) ^ srow) << 3;  // swizzled source chunk (elems)
  const f16* Ag = A + (size_t)(bm + wave * 16 + srow) * lda + kbeg + schunk;
  const f16* Bg = B + (size_t)(bn + wave * 16 + srow) * ldb + kbeg + schunk;

  // swizzled fragment k-offsets (elems within 64-elem row), kk = 0 / 1
  const int co0 = ((lkc ^ (lrow & 7)) << 3);
  const int co1 = (((4 + lkc) ^ (lrow & 7)) << 3);

  floatx4 acc[8][4] = {};
  half8 af[4][2];       // one qm-half of A frags, both kk
  half8 bf[2][2][2];    // [qn][fn][kk] -- both qn halves live

  auto STAGE = [&](int b, int tt, int h) {  // h: 0=A-lo 1=A-hi 2=B-lo 3=B-hi
    if (h < 2) {
      const f16* src = Ag + (size_t)(h * 128) * lda + tt * 64;
      f16* d = smp + (b * 2) * 16384 + h * 8192 + wave * 1024;
      gload_lds16(src, d);
      gload_lds16(src + (size_t)8 * lda, d + 512);
    } else {
      const f16* src = Bg + (size_t)((h - 2) * 128) * ldb + tt * 64;
      f16* d = smp + (b * 2 + 1) * 16384 + (h - 2) * 8192 + wave * 1024;
      gload_lds16(src, d);
      gload_lds16(src + (size_t)8 * ldb, d + 512);
    }
  };
  auto LDA = [&](int b, int qm) {
    const f16* base = smp + (b * 2) * 16384 + (wm + qm * 64 + lrow) * 64;
#pragma unroll
    for (int fm = 0; fm < 4; ++fm) {
      af[fm][0] = *(const half8*)(base + fm * (16 * 64) + co0);
      af[fm][1] = *(const half8*)(base + fm * (16 * 64) + co1);
    }
  };
  auto LDB = [&](int b, int qn) {
    const f16* base = smp + (b * 2 + 1) * 16384 + (wn + qn * 32 + lrow) * 64;
#pragma unroll
    for (int fn = 0; fn < 2; ++fn) {
      bf[qn][fn][0] = *(const half8*)(base + fn * (16 * 64) + co0);
      bf[qn][fn][1] = *(const half8*)(base + fn * (16 * 64) + co1);
    }
  };
  auto MFMAQ = [&](int qm, int qn) {
    __builtin_amdgcn_s_setprio(1);
#pragma unroll
    for (int kk = 0; kk < 2; ++kk)
#pragma unroll
      for (int fm = 0; fm < 4; ++fm)
#pragma unroll
        for (int fn = 0; fn < 2; ++fn)
          acc[qm * 4 + fm][qn * 2 + fn] =
              __builtin_amdgcn_mfma_f32_16x16x32_f16(
                  af[fm][kk], bf[qn][fn][kk], acc[qm * 4 + fm][qn * 2 + fn],
                  0, 0, 0);
    __builtin_amdgcn_s_setprio(0);
  };

  const int NT = kper >> 6;  // K-tiles (even for all call sites)
  const int NI = NT >> 1;

  // prologue: tile0 -> buf0 (4 halves), tile1 half0 -> buf1; wait tile0
  STAGE(0, 0, 0); STAGE(0, 0, 1); STAGE(0, 0, 2); STAGE(0, 0, 3);
  STAGE(1, 1, 0);
  WAIT_VM(2);
  BARRIER();

  for (int i = 0; i < NI; ++i) {
    const bool last = (i == NI - 1);
    const int tb = 2 * i;
    // P0 -- t0 Q(0,0)
    LDA(0, 0); LDB(0, 0); STAGE(1, tb + 1, 1);
    BARRIER(); MFMAQ(0, 0); BARRIER();
    // P1 -- t0 Q(0,1)
    LDB(0, 1); STAGE(1, tb + 1, 2);
    BARRIER(); MFMAQ(0, 1); BARRIER();
    // P2 -- t0 Q(1,0)
    LDA(0, 1); STAGE(1, tb + 1, 3);
    BARRIER(); MFMAQ(1, 0); BARRIER();
    // P3 -- t0 Q(1,1); guarantee tile t1 landed before P4 reads buf1
    if (!last) {
      STAGE(0, tb + 2, 0);
      WAIT_VM(2);
    } else {
      WAIT_VM(0);
    }
    BARRIER(); MFMAQ(1, 1); BARRIER();
    // P4 -- t1 Q(0,0)
    LDA(1, 0); LDB(1, 0);
    if (!last) STAGE(0, tb + 2, 1);
    BARRIER(); MFMAQ(0, 0); BARRIER();
    // P5 -- t1 Q(0,1)
    LDB(1, 1);
    if (!last) STAGE(0, tb + 2, 2);
    BARRIER(); MFMAQ(0, 1); BARRIER();
    // P6 -- t1 Q(1,0)
    LDA(1, 1);
    if (!last) STAGE(0, tb + 2, 3);
    BARRIER(); MFMAQ(1, 0); BARRIER();
    // P7 -- t1 Q(1,1); guarantee tile t0+2 landed before next P0 reads buf0
    if (!last) {
      STAGE(1, tb + 3, 0);
      WAIT_VM(2);
    }
    BARRIER(); MFMAQ(1, 1); BARRIER();
  }

  // epilogue: C/D col = lane&15, row = (lane>>4)*4 + reg
  const int crow0 = bm + wm + lkc * 4;
  const int ccol0 = bn + wn + lrow;
#pragma unroll
  for (int i = 0; i < 8; ++i) {
#pragma unroll
    for (int r2 = 0; r2 < 4; ++r2) {
      const size_t row = (size_t)(crow0 + i * 16 + r2);
#pragma unroll
      for (int j = 0; j < 4; ++j) {
        const int col = ccol0 + j * 16;
        float v = acc[i][j][r2];
        if (EPI == 2) v = fmaxf(v + bias[col], 0.0f);
        Cz[row * (size_t)ldc + col] = (f16)v;
      }
    }
  }
}

// bijective XCD-chunked swizzle (T1): block with HW id `id` (XCD = id%8)
// computes tile nid from its XCD's contiguous chunk.
__device__ __forceinline__ int xcd_swizzle(int id, int nwg) {
  const int q = nwg >> 3, r = nwg & 7;
  const int xcd = id & 7, lin = id >> 3;
  return (xcd < r ? xcd * (q + 1) : r * (q + 1) + (xcd - r) * q) + lin;
}

// ---------------------------------------------------------------------------
// generic NT wrapper: C = A*B^T, split-K via gridDim.z, f16 slabs at
// Ch + z*M*ldc.
// ---------------------------------------------------------------------------
template <int EPI>
__global__ __launch_bounds__(512, 2) void gemm_nt256(
    const f16* __restrict__ A, const f16* __restrict__ B,
    f16* __restrict__ Ch, const float* __restrict__ bias,
    int M, int Nc, int K, int lda, int ldb, int ldc) {
  __shared__ f16 sm[4][256 * 64];
  const int gx = gridDim.x, gy = gridDim.y;
  const int nwg = gx * gy * gridDim.z;
  const int id = blockIdx.x + gx * (blockIdx.y + gy * blockIdx.z);
  const int nid = xcd_swizzle(id, nwg);
  const int bx = nid % gx;
  const int by = (nid / gx) % gy;
  const int bz = nid / (gx * gy);
  const int kper = K / gridDim.z;
  gemm256_core<EPI>(A, B, Ch + (size_t)bz * M * ldc, bias, lda, ldb, ldc,
                    kper, bz * kper, by << 8, bx << 8, &sm[0][0]);
}

// ---------------------------------------------------------------------------
// weight precompose on the 8-phase core: grid (4,4,16).
// z<8: parQK slab zz = Wkb@Wqb^T (K=4096 split 8); z>=8: parVO = WoT@Wvb^T.
// ---------------------------------------------------------------------------
__global__ __launch_bounds__(512, 2) void gemm_pre256(
    const f16* __restrict__ Wkb, const f16* __restrict__ Wqb,
    const f16* __restrict__ WoT, const f16* __restrict__ Wvb,
    f16* __restrict__ parQK, f16* __restrict__ parVO, int D, int H) {
  __shared__ f16 sm[4][256 * 64];
  const int id = blockIdx.x + 4 * (blockIdx.y + 4 * blockIdx.z);
  const int nid = xcd_swizzle(id, 256);
  const int bx = nid & 3, by = (nid >> 2) & 3, z = nid >> 4;
  const int zz = z & 7;
  const f16* A = (z < 8) ? Wkb : WoT;
  const f16* B = (z < 8) ? Wqb : Wvb;
  f16* slab = ((z < 8) ? parQK : parVO) + (size_t)zz * D * D;
  gemm256_core<1>(A, B, slab, nullptr, H, H, D, H / 8, zz * (H / 8),
                  by << 8, bx << 8, &sm[0][0]);
}

// ---------------------------------------------------------------------------
// merged th/xvoT on the 8-phase core: grid (4,32).
// y<16: th = xb@WqkT^T [N,D] (bm=y,bn=x); y>=16: xvoT = WvoT@xb^T [D,N].
// ---------------------------------------------------------------------------
__global__ __launch_bounds__(512, 2) void gemm_dual256(
    const f16* __restrict__ xb, const f16* __restrict__ WqkT,
    const f16* __restrict__ WvoT, f16* __restrict__ th,
    f16* __restrict__ xvoT, int N, int D) {
  __shared__ f16 sm[4][256 * 64];
  const int id = blockIdx.x + 4 * blockIdx.y;
  const int nid = xcd_swizzle(id, 128);
  const int bx = nid & 3, y = nid >> 2;
  if (y < 16)
    gemm256_core<1>(xb, WqkT, th, nullptr, D, D, D, D, 0,
                    y << 8, bx << 8, &sm[0][0]);
  else
    gemm256_core<1>(WvoT, xb, xvoT, nullptr, D, D, N, D, 0,
                    bx << 8, (y - 16) << 8, &sm[0][0]);
}

// ---------------------------------------------------------------------------
// fused input prep (round-3 best-measured variant), grid (1024, 7), block 256.
// z 0..2: transposes via shfl 4x4 transpose + swizzled LDS (r^((c&15)<<2)).
// z 3..6: converts, 4x float4 in, 2x half8 out per lane.
// ---------------------------------------------------------------------------
__global__ void prep_inputs(const float* x, const float* Wq, const float* Wk,
                            const float* Wv, const float* W1, const float* Wo,
                            const float* W2, f16* xb, f16* Wqb, f16* Wkb,
                            f16* Wvb, f16* W1T, f16* WoT, f16* W2T) {
  const int z = blockIdx.y;
  const int b = blockIdx.x;
  const int t = threadIdx.x;
  if (z >= 3) {  // converts
    const float* in = (z == 3) ? x : (z == 4) ? Wq : (z == 5) ? Wk : Wv;
    f16* out = (z == 3) ? xb : (z == 4) ? Wqb : (z == 5) ? Wkb : Wvb;
    const size_t i = ((size_t)b * 256 + t) * 16;
    const float4 a0 = *(const float4*)(in + i);
    const float4 a1 = *(const float4*)(in + i + 4);
    const float4 a2 = *(const float4*)(in + i + 8);
    const float4 a3 = *(const float4*)(in + i + 12);
    half8 v0 = {(f16)a0.x, (f16)a0.y, (f16)a0.z, (f16)a0.w,
                (f16)a1.x, (f16)a1.y, (f16)a1.z, (f16)a1.w};
    half8 v1 = {(f16)a2.x, (f16)a2.y, (f16)a2.z, (f16)a2.w,
                (f16)a3.x, (f16)a3.y, (f16)a3.z, (f16)a3.w};
    *(half8*)(out + i) = v0;
    *(half8*)(out + i + 8) = v1;
    return;
  }
  int R, C, tx, ty;
  const float* in;
  f16* out;
  if (z == 0) {
    R = 1024; C = 4096; in = W1; out = W1T;
    tx = b & 63; ty = b >> 6;
  } else {
    R = 4096; C = 1024; in = (z == 1) ? Wo : W2;
    out = (z == 1) ? WoT : W2T;
    tx = b & 15; ty = b >> 4;
  }
  const int r0 = ty << 6, c0 = tx << 6;
  __shared__ f16 lt[64 * 64];
  const int lr = t >> 4;
  const int lc = t & 15;
  const int q3 = lr & 3;
  const int rb = lr & ~3;
  const int myc = lc * 4 + q3;
#pragma unroll
  for (int rr = 0; rr < 4; ++rr) {
    const int r = lr + rr * 16;
    const float4 f = *(const float4*)(in + (size_t)(r0 + r) * C + c0 + lc * 4);
    float v0 = f.x, v1 = f.y, v2 = f.z, v3 = f.w;
    // 4x4 transpose among lanes {t ^ 16, t ^ 32}: block swap (mask 32)...
    {
      const bool hi = (q3 & 2) != 0;
      float sA = hi ? v0 : v2;
      float sB = hi ? v1 : v3;
      sA = __shfl_xor(sA, 32);
      sB = __shfl_xor(sB, 32);
      if (hi) { v0 = sA; v1 = sB; } else { v2 = sA; v3 = sB; }
    }
    // ...then in-block 2x2 transpose (mask 16)
    {
      const bool od = (q3 & 1) != 0;
      float sC = od ? v0 : v1;
      float sD = od ? v2 : v3;
      sC = __shfl_xor(sC, 16);
      sD = __shfl_xor(sD, 16);
      if (od) { v0 = sC; v2 = sD; } else { v1 = sC; v3 = sD; }
    }
    half4 hv = {(f16)v0, (f16)v1, (f16)v2, (f16)v3};
    const int rbase = rb + rr * 16;
    *(half4*)(lt + myc * 64 + (rbase ^ ((myc & 15) << 2))) = hv;
  }
  __syncthreads();
  const int oc = t >> 3, orr = (t & 7) << 3;
#pragma unroll
  for (int cc = 0; cc < 2; ++cc) {
    const int c = oc + cc * 32;
    const int swz = (c & 15) << 2;
    const half4 ha = *(const half4*)(lt + c * 64 + (orr ^ swz));
    const half4 hb4 = *(const half4*)(lt + c * 64 + ((orr + 4) ^ swz));
    half8 v = {ha[0], ha[1], ha[2], ha[3], hb4[0], hb4[1], hb4[2], hb4[3]};
    *(half8*)(out + (size_t)(c0 + c) * R + r0 + orr) = v;
  }
}

// ---------------------------------------------------------------------------
// merged slab reduce: 16B/lane loads.
// ---------------------------------------------------------------------------
__global__ void reduce_dual(const f16* __restrict__ parQK,
                            const f16* __restrict__ parVO,
                            f16* __restrict__ WqkT, f16* __restrict__ WvoT,
                            int n) {
  const int half = gridDim.x >> 1;
  const bool second = blockIdx.x >= half;
  const f16* par = second ? parVO : parQK;
  f16* out = second ? WvoT : WqkT;
  const int b = second ? blockIdx.x - half : blockIdx.x;
  const int i = (b * 256 + threadIdx.x) * 8;
  float s[8] = {};
#pragma unroll
  for (int z = 0; z < 8; ++z) {
    const half8 p = *(const half8*)(par + (size_t)z * n + i);
#pragma unroll
    for (int k = 0; k < 8; ++k) s[k] += (float)p[k];
  }
  half8 o = {(f16)s[0], (f16)s[1], (f16)s[2], (f16)s[3],
             (f16)s[4], (f16)s[5], (f16)s[6], (f16)s[7]};
  *(half8*)(out + i) = o;
}

// ---------------------------------------------------------------------------
// row softmax: f16 S[row,:N] -> f16 P. One 256-thread block per row, N=4096.
// ---------------------------------------------------------------------------
__global__ void softmax_rows(const f16* __restrict__ S, f16* __restrict__ P,
                             int N) {
  const int row = blockIdx.x;
  const int t = threadIdx.x;
  const int lane = t & 63, wave = t >> 6;
  const f16* s = S + (size_t)row * N;
  const half8 a = *(const half8*)(s + t * 8);
  const half8 b = *(const half8*)(s + 2048 + t * 8);
  float v[16];
#pragma unroll
  for (int i = 0; i < 8; ++i) {
    v[i] = (float)a[i];
    v[8 + i] = (float)b[i];
  }
  float mx = -1e30f;
#pragma unroll
  for (int i = 0; i < 16; ++i) mx = fmaxf(mx, v[i]);
#pragma unroll
  for (int off = 32; off > 0; off >>= 1) mx = fmaxf(mx, __shfl_xor(mx, off));
  __shared__ float red[8];
  if (lane == 0) red[wave] = mx;
  __syncthreads();
  mx = fmaxf(fmaxf(red[0], red[1]), fmaxf(red[2], red[3]));
  float sum = 0.0f;
#pragma unroll
  for (int i = 0; i < 16; ++i) {
    v[i] = __expf(v[i] - mx);
    sum += v[i];
  }
#pragma unroll
  for (int off = 32; off > 0; off >>= 1) sum += __shfl_xor(sum, off);
  if (lane == 0) red[4 + wave] = sum;
  __syncthreads();
  const float inv = 1.0f / (red[4] + red[5] + red[6] + red[7]);
  f16* p = P + (size_t)row * N;
  half8 oa, ob;
#pragma unroll
  for (int i = 0; i < 8; ++i) {
    oa[i] = (f16)(v[i] * inv);
    ob[i] = (f16)(v[8 + i] * inv);
  }
  *(half8*)(p + t * 8) = oa;
  *(half8*)(p + 2048 + t * 8) = ob;
}

// ---------------------------------------------------------------------------
// fused residual + f16 split-K slab reduce + (optional bias) + LayerNorm.
// One 128-thread block per row, D=1024: 8 elems (16B slab loads) per lane.
// 2-wave reduction via LDS.
// ---------------------------------------------------------------------------
__global__ void add_ln(const float* __restrict__ a, const f16* __restrict__ b,
                       int nchunks, size_t cs, const float* __restrict__ bias,
                       const float* __restrict__ g, const float* __restrict__ be,
                       float* __restrict__ outf, f16* __restrict__ outh, int D) {
  const int row = blockIdx.x;
  const int t = threadIdx.x;
  const int lane = t & 63, wave = t >> 6;  // wave 0/1
  const size_t base = (size_t)row * D + t * 8;
  const float4 av0 = *(const float4*)(a + base);
  const float4 av1 = *(const float4*)(a + base + 4);
  float s[8] = {av0.x, av0.y, av0.z, av0.w, av1.x, av1.y, av1.z, av1.w};
  for (int c = 0; c < nchunks; ++c) {
    const half8 bv = *(const half8*)(b + c * cs + base);
#pragma unroll
    for (int k = 0; k < 8; ++k) s[k] += (float)bv[k];
  }
  if (bias != nullptr) {
    const float4 bb0 = *(const float4*)(bias + t * 8);
    const float4 bb1 = *(const float4*)(bias + t * 8 + 4);
    s[0] += bb0.x; s[1] += bb0.y; s[2] += bb0.z; s[3] += bb0.w;
    s[4] += bb1.x; s[5] += bb1.y; s[6] += bb1.z; s[7] += bb1.w;
  }
  float sum = 0.0f, sq = 0.0f;
#pragma unroll
  for (int k = 0; k < 8; ++k) {
    sum += s[k];
    sq += s[k] * s[k];
  }
#pragma unroll
  for (int off = 32; off > 0; off >>= 1) {
    sum += __shfl_xor(sum, off);
    sq += __shfl_xor(sq, off);
  }
  __shared__ float red[4];
  if (lane == 0) {
    red[wave] = sum;
    red[2 + wave] = sq;
  }
  __syncthreads();
  sum = red[0] + red[1];
  sq = red[2] + red[3];
  const float mu = sum / (float)D;
  const float rv = rsqrtf(sq / (float)D - mu * mu + LN_EPS);
  const float4 gv0 = *(const float4*)(g + t * 8);
  const float4 gv1 = *(const float4*)(g + t * 8 + 4);
  const float4 be0 = *(const float4*)(be + t * 8);
  const float4 be1 = *(const float4*)(be + t * 8 + 4);
  const float gg[8] = {gv0.x, gv0.y, gv0.z, gv0.w, gv1.x, gv1.y, gv1.z, gv1.w};
  const float bb[8] = {be0.x, be0.y, be0.z, be0.w, be1.x, be1.y, be1.z, be1.w};
  float y[8];
#pragma unroll
  for (int k = 0; k < 8; ++k) y[k] = (s[k] - mu) * rv * gg[k] + bb[k];
  if (outf != nullptr) {
    float4 o0 = {y[0], y[1], y[2], y[3]};
    float4 o1 = {y[4], y[5], y[6], y[7]};
    *(float4*)(outf + base) = o0;
    *(float4*)(outf + base + 4) = o1;
  }
  if (outh != nullptr) {
    half8 o = {(f16)y[0], (f16)y[1], (f16)y[2], (f16)y[3],
               (f16)y[4], (f16)y[5], (f16)y[6], (f16)y[7]};
    *(half8*)(outh + base) = o;
  }
}

// ---------------------------------------------------------------------------
// launch
// ---------------------------------------------------------------------------
extern "C" void kernel_launch(void* const* d_in, const int* in_sizes, int n_in,
                              void* d_out, int out_size, void* d_ws,
                              size_t ws_size, hipStream_t stream) {
  constexpr int N = 4096, D = 1024, H = 4096;
  const float* x = (const float*)d_in[0];
  const float* Wq = (const float*)d_in[1];
  const float* Wk = (const float*)d_in[2];
  const float* Wv = (const float*)d_in[3];
  const float* Wo = (const float*)d_in[4];
  const float* W1 = (const float*)d_in[5];
  const float* b1 = (const float*)d_in[6];
  const float* W2 = (const float*)d_in[7];
  const float* b2 = (const float*)d_in[8];
  const float* g1 = (const float*)d_in[9];
  const float* be1 = (const float*)d_in[10];
  const float* g2 = (const float*)d_in[11];
  const float* be2 = (const float*)d_in[12];
  float* out = (float*)d_out;

  const size_t MB = 1024ull * 1024ull;
  char* w = (char*)d_ws;
  // workspace layout (228 MB used; hazard-checked reuse; offsets in MB):
  f16* xb   = (f16*)(w + 0 * MB);     // 8   [N,D]
  f16* Wqb  = (f16*)(w + 8 * MB);     // 8   [D,H]
  f16* Wkb  = (f16*)(w + 16 * MB);    // 8   [D,H]
  f16* Wvb  = (f16*)(w + 24 * MB);    // 8   [D,H]
  f16* WoT  = (f16*)(w + 32 * MB);    // 8   [D,H]
  f16* W1T  = (f16*)(w + 40 * MB);    // 8   [H,D]
  f16* W2T  = (f16*)(w + 48 * MB);    // 8   [D,H]
  f16* WqkT = (f16*)(w + 56 * MB);    // 2   [D,D] = (Wq@Wk^T)^T
  f16* WvoT = (f16*)(w + 58 * MB);    // 2   [D,D] = (Wv@Wo)^T
  f16* th   = (f16*)(w + 60 * MB);    // 8   [N,D]; dead after S
  f16* xvoT = (f16*)(w + 68 * MB);    // 8   [D,N]
  f16* F1   = (f16*)(w + 76 * MB);    // 32  [N,H]
  f16* Sh   = (f16*)(w + 108 * MB);   // 32  [N,N] f16; dead after softmax
  f16* parA = (f16*)(w + 108 * MB);   // 4x8MB f16 slabs (over dead Sh)
  f16* Pb   = (f16*)(w + 140 * MB);   // 32  [N,N]; dead after attn
  float* hf = (float*)(w + 172 * MB); // 16  [N,D]
  f16* hb   = (f16*)(w + 188 * MB);   // 8   [N,D]
  f16* parQK = (f16*)(w + 196 * MB);  // 16 = 8x2MB f16 slabs; dead after reduce
  f16* parVO = (f16*)(w + 212 * MB);  // 16 = 8x2MB f16 slabs; dead after reduce

  // ---- input prep: 4 converts + 3 transposes, ONE dispatch ----
  prep_inputs<<<dim3(1024, 7), 256, 0, stream>>>(
      x, Wq, Wk, Wv, W1, Wo, W2, xb, Wqb, Wkb, Wvb, W1T, WoT, W2T);

  // ---- weight precomposition (both [D,D] composites, one dispatch) ----
  gemm_pre256<<<dim3(4, 4, 16), 512, 0, stream>>>(
      Wkb, Wqb, WoT, Wvb, parQK, parVO, D, H);
  reduce_dual<<<2 * (D * D) / 2048, 256, 0, stream>>>(parQK, parVO, WqkT,
                                                      WvoT, D * D);

  // ---- attention ----
  // th = xb@WqkT^T [N,D] and xvoT = WvoT@xb^T [D,N], one dispatch
  gemm_dual256<<<dim3(4, 32), 512, 0, stream>>>(xb, WqkT, WvoT, th, xvoT,
                                                N, D);
  // S = th @ xb^T  [N,N] f16 logits (K=1024), 256^2 8-phase kernel
  gemm_nt256<1><<<dim3(N / 256, N / 256, 1), 512, 0, stream>>>(
      th, xb, Sh, nullptr, N, N, D, D, D, N);
  softmax_rows<<<N, 256, 0, stream>>>(Sh, Pb, N);
  // attn partials = Pb @ xvoT^T  [N,D], split-K=4, f16 slabs (over dead Sh)
  gemm_nt256<1><<<dim3(D / 256, N / 256, 4), 512, 0, stream>>>(
      Pb, xvoT, parA, nullptr, N, D, N, N, N, D);
  // h = LN(x + sum(attn partials))
  add_ln<<<N, 128, 0, stream>>>(x, parA, 4, (size_t)N * D, nullptr, g1, be1,
                                hf, hb, D);

  // ---- feed-forward ----
  // F1 = relu(hb @ W1T^T + b1)  [N,H] f16
  gemm_nt256<2><<<dim3(H / 256, N / 256, 1), 512, 0, stream>>>(
      hb, W1T, F1, b1, N, H, D, D, D, H);
  // F2 partials = F1 @ W2T^T  [N,D], split-K=4, f16 slabs
  gemm_nt256<1><<<dim3(D / 256, N / 256, 4), 512, 0, stream>>>(
      F1, W2T, parA, nullptr, N, D, H, H, H, D);
  // out = LN(hf + sum(F2 partials) + b2)
  add_ln<<<N, 128, 0, stream>>>(hf, parA, 4, (size_t)N * D, b2, g2, be2,
                                out, nullptr, D);
}

// Round 8
// 407.248 us; speedup vs baseline: 1.2057x; 1.0157x over previous
//
#include <hip/hip_runtime.h>
#include <hip/hip_bf16.h>

using f16 = _Float16;
typedef __attribute__((ext_vector_type(8))) f16 half8;
typedef __attribute__((ext_vector_type(4))) f16 half4;
typedef __attribute__((ext_vector_type(4))) float floatx4;

#define LN_EPS 1e-5f

// ---------------------------------------------------------------------------
// async global->LDS, 16B per lane. LDS dest is wave-uniform base + lane*16.
// ---------------------------------------------------------------------------
__device__ __forceinline__ void gload_lds16(const f16* g, f16* l) {
  __builtin_amdgcn_global_load_lds(
      (const __attribute__((address_space(1))) void*)g,
      (__attribute__((address_space(3))) void*)l, 16, 0, 0);
}

#define CFENCE asm volatile("" ::: "memory")
#define WAIT_VM(N) asm volatile("s_waitcnt vmcnt(" #N ")" ::: "memory")
#define BARRIER()                    \
  do {                               \
    CFENCE;                          \
    __builtin_amdgcn_s_barrier();    \
    CFENCE;                          \
  } while (0)

// ---------------------------------------------------------------------------
// 256x256-tile 8-phase pipelined GEMM core (T1+T2+T3+T4+T5), 512 thr
// (8 waves, 2Mx4N), BK=64, per-wave output 128x64 (acc[8][4] f32x4),
// 128 KiB LDS (2 K-tile buffers x (A 256x64 + B 256x64) f16).
// Schedule identical to the round-1 harness-verified kernel.
// ---------------------------------------------------------------------------
template <int EPI>
__device__ __forceinline__ void gemm256_core(
    const f16* __restrict__ A, const f16* __restrict__ B,
    f16* __restrict__ Ch, const float* __restrict__ bias,
    int lda, int ldb, int ldc, int kper, int kbeg, int bm, int bn,
    f16* smp) {
  const int t = threadIdx.x;
  const int wave = t >> 6, lane = t & 63;
  const int wm = (wave >> 2) << 7;  // wave M offset: 0/128
  const int wn = (wave & 3) << 6;   // wave N offset: 0/64/128/192
  const int lrow = lane & 15, lkc = lane >> 4;

  // staging: seg = wave*2+l covers 8 rows of a 128-row half-tile
  const int srow = lane >> 3;
  const int schunk = ((lane & 7) ^ srow) << 3;  // swizzled source chunk (elems)
  const f16* Ag = A + (size_t)(bm + wave * 16 + srow) * lda + kbeg + schunk;
  const f16* Bg = B + (size_t)(bn + wave * 16 + srow) * ldb + kbeg + schunk;

  // swizzled fragment k-offsets (elems within 64-elem row), kk = 0 / 1
  const int co0 = ((lkc ^ (lrow & 7)) << 3);
  const int co1 = (((4 + lkc) ^ (lrow & 7)) << 3);

  floatx4 acc[8][4] = {};
  half8 af[4][2];       // one qm-half of A frags, both kk
  half8 bf[2][2][2];    // [qn][fn][kk] -- both qn halves live

  auto STAGE = [&](int b, int tt, int h) {  // h: 0=A-lo 1=A-hi 2=B-lo 3=B-hi
    if (h < 2) {
      const f16* src = Ag + (size_t)(h * 128) * lda + tt * 64;
      f16* d = smp + (b * 2) * 16384 + h * 8192 + wave * 1024;
      gload_lds16(src, d);
      gload_lds16(src + (size_t)8 * lda, d + 512);
    } else {
      const f16* src = Bg + (size_t)((h - 2) * 128) * ldb + tt * 64;
      f16* d = smp + (b * 2 + 1) * 16384 + (h - 2) * 8192 + wave * 1024;
      gload_lds16(src, d);
      gload_lds16(src + (size_t)8 * ldb, d + 512);
    }
  };
  auto LDA = [&](int b, int qm) {
    const f16* base = smp + (b * 2) * 16384 + (wm + qm * 64 + lrow) * 64;
#pragma unroll
    for (int fm = 0; fm < 4; ++fm) {
      af[fm][0] = *(const half8*)(base + fm * (16 * 64) + co0);
      af[fm][1] = *(const half8*)(base + fm * (16 * 64) + co1);
    }
  };
  auto LDB = [&](int b, int qn) {
    const f16* base = smp + (b * 2 + 1) * 16384 + (wn + qn * 32 + lrow) * 64;
#pragma unroll
    for (int fn = 0; fn < 2; ++fn) {
      bf[qn][fn][0] = *(const half8*)(base + fn * (16 * 64) + co0);
      bf[qn][fn][1] = *(const half8*)(base + fn * (16 * 64) + co1);
    }
  };
  auto MFMAQ = [&](int qm, int qn) {
    __builtin_amdgcn_s_setprio(1);
#pragma unroll
    for (int kk = 0; kk < 2; ++kk)
#pragma unroll
      for (int fm = 0; fm < 4; ++fm)
#pragma unroll
        for (int fn = 0; fn < 2; ++fn)
          acc[qm * 4 + fm][qn * 2 + fn] =
              __builtin_amdgcn_mfma_f32_16x16x32_f16(
                  af[fm][kk], bf[qn][fn][kk], acc[qm * 4 + fm][qn * 2 + fn],
                  0, 0, 0);
    __builtin_amdgcn_s_setprio(0);
  };

  const int NT = kper >> 6;  // K-tiles (even for all call sites)
  const int NI = NT >> 1;

  // prologue: tile0 -> buf0 (4 halves), tile1 half0 -> buf1; wait tile0
  STAGE(0, 0, 0); STAGE(0, 0, 1); STAGE(0, 0, 2); STAGE(0, 0, 3);
  STAGE(1, 1, 0);
  WAIT_VM(2);
  BARRIER();

  for (int i = 0; i < NI; ++i) {
    const bool last = (i == NI - 1);
    const int tb = 2 * i;
    // P0 -- t0 Q(0,0)
    LDA(0, 0); LDB(0, 0); STAGE(1, tb + 1, 1);
    BARRIER(); MFMAQ(0, 0); BARRIER();
    // P1 -- t0 Q(0,1)
    LDB(0, 1); STAGE(1, tb + 1, 2);
    BARRIER(); MFMAQ(0, 1); BARRIER();
    // P2 -- t0 Q(1,0)
    LDA(0, 1); STAGE(1, tb + 1, 3);
    BARRIER(); MFMAQ(1, 0); BARRIER();
    // P3 -- t0 Q(1,1); guarantee tile t1 landed before P4 reads buf1
    if (!last) {
      STAGE(0, tb + 2, 0);
      WAIT_VM(2);
    } else {
      WAIT_VM(0);
    }
    BARRIER(); MFMAQ(1, 1); BARRIER();
    // P4 -- t1 Q(0,0)
    LDA(1, 0); LDB(1, 0);
    if (!last) STAGE(0, tb + 2, 1);
    BARRIER(); MFMAQ(0, 0); BARRIER();
    // P5 -- t1 Q(0,1)
    LDB(1, 1);
    if (!last) STAGE(0, tb + 2, 2);
    BARRIER(); MFMAQ(0, 1); BARRIER();
    // P6 -- t1 Q(1,0)
    LDA(1, 1);
    if (!last) STAGE(0, tb + 2, 3);
    BARRIER(); MFMAQ(1, 0); BARRIER();
    // P7 -- t1 Q(1,1); guarantee tile t0+2 landed before next P0 reads buf0
    if (!last) {
      STAGE(1, tb + 3, 0);
      WAIT_VM(2);
    }
    BARRIER(); MFMAQ(1, 1); BARRIER();
  }

  // epilogue: C/D col = lane&15, row = (lane>>4)*4 + reg
  const int crow0 = bm + wm + lkc * 4;
  const int ccol0 = bn + wn + lrow;
#pragma unroll
  for (int i = 0; i < 8; ++i) {
#pragma unroll
    for (int r2 = 0; r2 < 4; ++r2) {
      const size_t row = (size_t)(crow0 + i * 16 + r2);
#pragma unroll
      for (int j = 0; j < 4; ++j) {
        const int col = ccol0 + j * 16;
        float v = acc[i][j][r2];
        if (EPI == 2) v = fmaxf(v + bias[col], 0.0f);
        Ch[row * (size_t)ldc + col] = (f16)v;
      }
    }
  }
}

// bijective XCD-chunked swizzle (T1): block with HW id `id` (XCD = id%8)
// computes tile nid from its XCD's contiguous chunk.
__device__ __forceinline__ int xcd_swizzle(int id, int nwg) {
  const int q = nwg >> 3, r = nwg & 7;
  const int xcd = id & 7, lin = id >> 3;
  return (xcd < r ? xcd * (q + 1) : r * (q + 1) + (xcd - r) * q) + lin;
}

// ---------------------------------------------------------------------------
// generic NT wrapper: C = A*B^T, split-K via gridDim.z, f16 slabs at
// Ch + z*M*ldc.
// ---------------------------------------------------------------------------
template <int EPI>
__global__ __launch_bounds__(512, 2) void gemm_nt256(
    const f16* __restrict__ A, const f16* __restrict__ B,
    f16* __restrict__ Ch, const float* __restrict__ bias,
    int M, int Nc, int K, int lda, int ldb, int ldc) {
  __shared__ f16 sm[4][256 * 64];
  const int gx = gridDim.x, gy = gridDim.y;
  const int nwg = gx * gy * gridDim.z;
  const int id = blockIdx.x + gx * (blockIdx.y + gy * blockIdx.z);
  const int nid = xcd_swizzle(id, nwg);
  const int bx = nid % gx;
  const int by = (nid / gx) % gy;
  const int bz = nid / (gx * gy);
  const int kper = K / gridDim.z;
  gemm256_core<EPI>(A, B, Ch + (size_t)bz * M * ldc, bias, lda, ldb, ldc,
                    kper, bz * kper, by << 8, bx << 8, &sm[0][0]);
}

// ---------------------------------------------------------------------------
// weight precompose on the 8-phase core: grid (4,4,16).
// z<8: parQK slab zz = Wkb@Wqb^T (K=4096 split 8); z>=8: parVO = WoT@Wvb^T.
// ---------------------------------------------------------------------------
__global__ __launch_bounds__(512, 2) void gemm_pre256(
    const f16* __restrict__ Wkb, const f16* __restrict__ Wqb,
    const f16* __restrict__ WoT, const f16* __restrict__ Wvb,
    f16* __restrict__ parQK, f16* __restrict__ parVO, int D, int H) {
  __shared__ f16 sm[4][256 * 64];
  const int id = blockIdx.x + 4 * (blockIdx.y + 4 * blockIdx.z);
  const int nid = xcd_swizzle(id, 256);
  const int bx = nid & 3, by = (nid >> 2) & 3, z = nid >> 4;
  const int zz = z & 7;
  const f16* A = (z < 8) ? Wkb : WoT;
  const f16* B = (z < 8) ? Wqb : Wvb;
  f16* slab = ((z < 8) ? parQK : parVO) + (size_t)zz * D * D;
  gemm256_core<1>(A, B, slab, nullptr, H, H, D, H / 8, zz * (H / 8),
                  by << 8, bx << 8, &sm[0][0]);
}

// ---------------------------------------------------------------------------
// merged th/xvoT on the 8-phase core: grid (4,32).
// y<16: th = xb@WqkT^T [N,D] (bm=y,bn=x); y>=16: xvoT = WvoT@xb^T [D,N].
// ---------------------------------------------------------------------------
__global__ __launch_bounds__(512, 2) void gemm_dual256(
    const f16* __restrict__ xb, const f16* __restrict__ WqkT,
    const f16* __restrict__ WvoT, f16* __restrict__ th,
    f16* __restrict__ xvoT, int N, int D) {
  __shared__ f16 sm[4][256 * 64];
  const int id = blockIdx.x + 4 * blockIdx.y;
  const int nid = xcd_swizzle(id, 128);
  const int bx = nid & 3, y = nid >> 2;
  if (y < 16)
    gemm256_core<1>(xb, WqkT, th, nullptr, D, D, D, D, 0,
                    y << 8, bx << 8, &sm[0][0]);
  else
    gemm256_core<1>(WvoT, xb, xvoT, nullptr, D, D, N, D, 0,
                    bx << 8, (y - 16) << 8, &sm[0][0]);
}

// ---------------------------------------------------------------------------
// fused input prep (round-3 best-measured variant), grid (1024, 7), block 256.
// z 0..2: transposes via shfl 4x4 transpose + swizzled LDS (r^((c&15)<<2)).
// z 3..6: converts, 4x float4 in, 2x half8 out per lane.
// ---------------------------------------------------------------------------
__global__ void prep_inputs(const float* x, const float* Wq, const float* Wk,
                            const float* Wv, const float* W1, const float* Wo,
                            const float* W2, f16* xb, f16* Wqb, f16* Wkb,
                            f16* Wvb, f16* W1T, f16* WoT, f16* W2T) {
  const int z = blockIdx.y;
  const int b = blockIdx.x;
  const int t = threadIdx.x;
  if (z >= 3) {  // converts
    const float* in = (z == 3) ? x : (z == 4) ? Wq : (z == 5) ? Wk : Wv;
    f16* out = (z == 3) ? xb : (z == 4) ? Wqb : (z == 5) ? Wkb : Wvb;
    const size_t i = ((size_t)b * 256 + t) * 16;
    const float4 a0 = *(const float4*)(in + i);
    const float4 a1 = *(const float4*)(in + i + 4);
    const float4 a2 = *(const float4*)(in + i + 8);
    const float4 a3 = *(const float4*)(in + i + 12);
    half8 v0 = {(f16)a0.x, (f16)a0.y, (f16)a0.z, (f16)a0.w,
                (f16)a1.x, (f16)a1.y, (f16)a1.z, (f16)a1.w};
    half8 v1 = {(f16)a2.x, (f16)a2.y, (f16)a2.z, (f16)a2.w,
                (f16)a3.x, (f16)a3.y, (f16)a3.z, (f16)a3.w};
    *(half8*)(out + i) = v0;
    *(half8*)(out + i + 8) = v1;
    return;
  }
  int R, C, tx, ty;
  const float* in;
  f16* out;
  if (z == 0) {
    R = 1024; C = 4096; in = W1; out = W1T;
    tx = b & 63; ty = b >> 6;
  } else {
    R = 4096; C = 1024; in = (z == 1) ? Wo : W2;
    out = (z == 1) ? WoT : W2T;
    tx = b & 15; ty = b >> 4;
  }
  const int r0 = ty << 6, c0 = tx << 6;
  __shared__ f16 lt[64 * 64];
  const int lr = t >> 4;
  const int lc = t & 15;
  const int q3 = lr & 3;
  const int rb = lr & ~3;
  const int myc = lc * 4 + q3;
#pragma unroll
  for (int rr = 0; rr < 4; ++rr) {
    const int r = lr + rr * 16;
    const float4 f = *(const float4*)(in + (size_t)(r0 + r) * C + c0 + lc * 4);
    float v0 = f.x, v1 = f.y, v2 = f.z, v3 = f.w;
    // 4x4 transpose among lanes {t ^ 16, t ^ 32}: block swap (mask 32)...
    {
      const bool hi = (q3 & 2) != 0;
      float sA = hi ? v0 : v2;
      float sB = hi ? v1 : v3;
      sA = __shfl_xor(sA, 32);
      sB = __shfl_xor(sB, 32);
      if (hi) { v0 = sA; v1 = sB; } else { v2 = sA; v3 = sB; }
    }
    // ...then in-block 2x2 transpose (mask 16)
    {
      const bool od = (q3 & 1) != 0;
      float sC = od ? v0 : v1;
      float sD = od ? v2 : v3;
      sC = __shfl_xor(sC, 16);
      sD = __shfl_xor(sD, 16);
      if (od) { v0 = sC; v2 = sD; } else { v1 = sC; v3 = sD; }
    }
    half4 hv = {(f16)v0, (f16)v1, (f16)v2, (f16)v3};
    const int rbase = rb + rr * 16;
    *(half4*)(lt + myc * 64 + (rbase ^ ((myc & 15) << 2))) = hv;
  }
  __syncthreads();
  const int oc = t >> 3, orr = (t & 7) << 3;
#pragma unroll
  for (int cc = 0; cc < 2; ++cc) {
    const int c = oc + cc * 32;
    const int swz = (c & 15) << 2;
    const half4 ha = *(const half4*)(lt + c * 64 + (orr ^ swz));
    const half4 hb4 = *(const half4*)(lt + c * 64 + ((orr + 4) ^ swz));
    half8 v = {ha[0], ha[1], ha[2], ha[3], hb4[0], hb4[1], hb4[2], hb4[3]};
    *(half8*)(out + (size_t)(c0 + c) * R + r0 + orr) = v;
  }
}

// ---------------------------------------------------------------------------
// merged slab reduce (round-3 exact): first half of blocks sum 8 f16 slabs
// parQK -> WqkT, second half parVO -> WvoT. n = D*D.
// ---------------------------------------------------------------------------
__global__ void reduce_dual(const f16* __restrict__ parQK,
                            const f16* __restrict__ parVO,
                            f16* __restrict__ WqkT, f16* __restrict__ WvoT,
                            int n) {
  const int half = gridDim.x >> 1;
  const bool second = blockIdx.x >= half;
  const f16* par = second ? parVO : parQK;
  f16* out = second ? WvoT : WqkT;
  const int b = second ? blockIdx.x - half : blockIdx.x;
  const int i = (b * 256 + threadIdx.x) * 4;
  float s0 = 0, s1 = 0, s2 = 0, s3 = 0;
#pragma unroll
  for (int z = 0; z < 8; ++z) {
    const half4 p = *(const half4*)(par + (size_t)z * n + i);
    s0 += (float)p[0]; s1 += (float)p[1]; s2 += (float)p[2]; s3 += (float)p[3];
  }
  half4 o = {(f16)s0, (f16)s1, (f16)s2, (f16)s3};
  *(half4*)(out + i) = o;
}

// ---------------------------------------------------------------------------
// row softmax: f16 S[row,:N] -> f16 P. One 256-thread block per row, N=4096.
// ---------------------------------------------------------------------------
__global__ void softmax_rows(const f16* __restrict__ S, f16* __restrict__ P,
                             int N) {
  const int row = blockIdx.x;
  const int t = threadIdx.x;
  const int lane = t & 63, wave = t >> 6;
  const f16* s = S + (size_t)row * N;
  const half8 a = *(const half8*)(s + t * 8);
  const half8 b = *(const half8*)(s + 2048 + t * 8);
  float v[16];
#pragma unroll
  for (int i = 0; i < 8; ++i) {
    v[i] = (float)a[i];
    v[8 + i] = (float)b[i];
  }
  float mx = -1e30f;
#pragma unroll
  for (int i = 0; i < 16; ++i) mx = fmaxf(mx, v[i]);
#pragma unroll
  for (int off = 32; off > 0; off >>= 1) mx = fmaxf(mx, __shfl_xor(mx, off));
  __shared__ float red[8];
  if (lane == 0) red[wave] = mx;
  __syncthreads();
  mx = fmaxf(fmaxf(red[0], red[1]), fmaxf(red[2], red[3]));
  float sum = 0.0f;
#pragma unroll
  for (int i = 0; i < 16; ++i) {
    v[i] = __expf(v[i] - mx);
    sum += v[i];
  }
#pragma unroll
  for (int off = 32; off > 0; off >>= 1) sum += __shfl_xor(sum, off);
  if (lane == 0) red[4 + wave] = sum;
  __syncthreads();
  const float inv = 1.0f / (red[4] + red[5] + red[6] + red[7]);
  f16* p = P + (size_t)row * N;
  half8 oa, ob;
#pragma unroll
  for (int i = 0; i < 8; ++i) {
    oa[i] = (f16)(v[i] * inv);
    ob[i] = (f16)(v[8 + i] * inv);
  }
  *(half8*)(p + t * 8) = oa;
  *(half8*)(p + 2048 + t * 8) = ob;
}

// ---------------------------------------------------------------------------
// fused residual + f16 split-K slab reduce + (optional bias) + LayerNorm.
// One 256-thread block per row, D=1024 (round-3 form). NCH is compile-time
// so the residual + NCH slab loads all issue back-to-back (ILP).
// ---------------------------------------------------------------------------
template <int NCH>
__global__ void add_ln(const float* __restrict__ a, const f16* __restrict__ b,
                       size_t cs, const float* __restrict__ bias,
                       const float* __restrict__ g, const float* __restrict__ be,
                       float* __restrict__ outf, f16* __restrict__ outh, int D) {
  const int row = blockIdx.x;
  const int t = threadIdx.x;
  const int lane = t & 63, wave = t >> 6;
  const float4 av = *(const float4*)(a + (size_t)row * D + t * 4);
  half4 bv[NCH];
#pragma unroll
  for (int c = 0; c < NCH; ++c)
    bv[c] = *(const half4*)(b + c * cs + (size_t)row * D + t * 4);
  float s[4] = {av.x, av.y, av.z, av.w};
#pragma unroll
  for (int c = 0; c < NCH; ++c) {
    s[0] += (float)bv[c][0]; s[1] += (float)bv[c][1];
    s[2] += (float)bv[c][2]; s[3] += (float)bv[c][3];
  }
  if (bias != nullptr) {
    const float4 bb = *(const float4*)(bias + t * 4);
    s[0] += bb.x; s[1] += bb.y; s[2] += bb.z; s[3] += bb.w;
  }
  float sum = s[0] + s[1] + s[2] + s[3];
  float sq = s[0] * s[0] + s[1] * s[1] + s[2] * s[2] + s[3] * s[3];
#pragma unroll
  for (int off = 32; off > 0; off >>= 1) {
    sum += __shfl_xor(sum, off);
    sq += __shfl_xor(sq, off);
  }
  __shared__ float red[8];
  if (lane == 0) {
    red[wave] = sum;
    red[4 + wave] = sq;
  }
  __syncthreads();
  sum = red[0] + red[1] + red[2] + red[3];
  sq = red[4] + red[5] + red[6] + red[7];
  const float mu = sum / (float)D;
  const float rv = rsqrtf(sq / (float)D - mu * mu + LN_EPS);
  const float4 gv = *(const float4*)(g + t * 4);
  const float4 bev = *(const float4*)(be + t * 4);
  float y0 = (s[0] - mu) * rv * gv.x + bev.x;
  float y1 = (s[1] - mu) * rv * gv.y + bev.y;
  float y2 = (s[2] - mu) * rv * gv.z + bev.z;
  float y3 = (s[3] - mu) * rv * gv.w + bev.w;
  if (outf != nullptr) {
    float4 o = {y0, y1, y2, y3};
    *(float4*)(outf + (size_t)row * D + t * 4) = o;
  }
  if (outh != nullptr) {
    f16* ob = outh + (size_t)row * D + t * 4;
    ob[0] = (f16)y0;
    ob[1] = (f16)y1;
    ob[2] = (f16)y2;
    ob[3] = (f16)y3;
  }
}

// ---------------------------------------------------------------------------
// launch
// ---------------------------------------------------------------------------
extern "C" void kernel_launch(void* const* d_in, const int* in_sizes, int n_in,
                              void* d_out, int out_size, void* d_ws,
                              size_t ws_size, hipStream_t stream) {
  constexpr int N = 4096, D = 1024, H = 4096;
  const float* x = (const float*)d_in[0];
  const float* Wq = (const float*)d_in[1];
  const float* Wk = (const float*)d_in[2];
  const float* Wv = (const float*)d_in[3];
  const float* Wo = (const float*)d_in[4];
  const float* W1 = (const float*)d_in[5];
  const float* b1 = (const float*)d_in[6];
  const float* W2 = (const float*)d_in[7];
  const float* b2 = (const float*)d_in[8];
  const float* g1 = (const float*)d_in[9];
  const float* be1 = (const float*)d_in[10];
  const float* g2 = (const float*)d_in[11];
  const float* be2 = (const float*)d_in[12];
  float* out = (float*)d_out;

  const size_t MB = 1024ull * 1024ull;
  char* w = (char*)d_ws;
  // workspace layout (228 MB used; hazard-checked reuse; offsets in MB):
  f16* xb   = (f16*)(w + 0 * MB);     // 8   [N,D]
  f16* Wqb  = (f16*)(w + 8 * MB);     // 8   [D,H]
  f16* Wkb  = (f16*)(w + 16 * MB);    // 8   [D,H]
  f16* Wvb  = (f16*)(w + 24 * MB);    // 8   [D,H]
  f16* WoT  = (f16*)(w + 32 * MB);    // 8   [D,H]
  f16* W1T  = (f16*)(w + 40 * MB);    // 8   [H,D]
  f16* W2T  = (f16*)(w + 48 * MB);    // 8   [D,H]
  f16* WqkT = (f16*)(w + 56 * MB);    // 2   [D,D] = (Wq@Wk^T)^T
  f16* WvoT = (f16*)(w + 58 * MB);    // 2   [D,D] = (Wv@Wo)^T
  f16* th   = (f16*)(w + 60 * MB);    // 8   [N,D]; dead after S
  f16* xvoT = (f16*)(w + 68 * MB);    // 8   [D,N]
  f16* F1   = (f16*)(w + 76 * MB);    // 32  [N,H]
  f16* Sh   = (f16*)(w + 108 * MB);   // 32  [N,N] f16; dead after softmax
  f16* parA = (f16*)(w + 108 * MB);   // 4x8MB f16 slabs (over dead Sh)
  f16* Pb   = (f16*)(w + 140 * MB);   // 32  [N,N]; dead after attn
  float* hf = (float*)(w + 172 * MB); // 16  [N,D]
  f16* hb   = (f16*)(w + 188 * MB);   // 8   [N,D]
  f16* parQK = (f16*)(w + 196 * MB);  // 16 = 8x2MB f16 slabs; dead after reduce
  f16* parVO = (f16*)(w + 212 * MB);  // 16 = 8x2MB f16 slabs; dead after reduce

  // ---- input prep: 4 converts + 3 transposes, ONE dispatch ----
  prep_inputs<<<dim3(1024, 7), 256, 0, stream>>>(
      x, Wq, Wk, Wv, W1, Wo, W2, xb, Wqb, Wkb, Wvb, W1T, WoT, W2T);

  // ---- weight precomposition (both [D,D] composites, one dispatch) ----
  gemm_pre256<<<dim3(4, 4, 16), 512, 0, stream>>>(
      Wkb, Wqb, WoT, Wvb, parQK, parVO, D, H);
  reduce_dual<<<2 * (D * D) / 1024, 256, 0, stream>>>(parQK, parVO, WqkT,
                                                      WvoT, D * D);

  // ---- attention ----
  // th = xb@WqkT^T [N,D] and xvoT = WvoT@xb^T [D,N], one dispatch
  gemm_dual256<<<dim3(4, 32), 512, 0, stream>>>(xb, WqkT, WvoT, th, xvoT,
                                                N, D);
  // S = th @ xb^T  [N,N] f16 logits (K=1024), 256^2 8-phase kernel
  gemm_nt256<1><<<dim3(N / 256, N / 256, 1), 512, 0, stream>>>(
      th, xb, Sh, nullptr, N, N, D, D, D, N);
  softmax_rows<<<N, 256, 0, stream>>>(Sh, Pb, N);
  // attn partials = Pb @ xvoT^T  [N,D], split-K=4, f16 slabs (over dead Sh)
  gemm_nt256<1><<<dim3(D / 256, N / 256, 4), 512, 0, stream>>>(
      Pb, xvoT, parA, nullptr, N, D, N, N, N, D);
  // h = LN(x + sum(attn partials))
  add_ln<4><<<N, 256, 0, stream>>>(x, parA, (size_t)N * D, nullptr, g1, be1,
                                   hf, hb, D);

  // ---- feed-forward ----
  // F1 = relu(hb @ W1T^T + b1)  [N,H] f16
  gemm_nt256<2><<<dim3(H / 256, N / 256, 1), 512, 0, stream>>>(
      hb, W1T, F1, b1, N, H, D, D, D, H);
  // F2 partials = F1 @ W2T^T  [N,D], split-K=4, f16 slabs
  gemm_nt256<1><<<dim3(D / 256, N / 256, 4), 512, 0, stream>>>(
      F1, W2T, parA, nullptr, N, D, H, H, H, D);
  // out = LN(hf + sum(F2 partials) + b2)
  add_ln<4><<<N, 256, 0, stream>>>(hf, parA, (size_t)N * D, b2, g2, be2,
                                   out, nullptr, D);
}

// Round 9
// 404.373 us; speedup vs baseline: 1.2143x; 1.0071x over previous
//
#include <hip/hip_runtime.h>
#include <hip/hip_bf16.h>

using f16 = _Float16;
typedef __attribute__((ext_vector_type(8))) f16 half8;
typedef __attribute__((ext_vector_type(4))) f16 half4;
typedef __attribute__((ext_vector_type(4))) float floatx4;

#define LN_EPS 1e-5f

// ---------------------------------------------------------------------------
// async global->LDS, 16B per lane. LDS dest is wave-uniform base + lane*16.
// ---------------------------------------------------------------------------
__device__ __forceinline__ void gload_lds16(const f16* g, f16* l) {
  __builtin_amdgcn_global_load_lds(
      (const __attribute__((address_space(1))) void*)g,
      (__attribute__((address_space(3))) void*)l, 16, 0, 0);
}

#define CFENCE asm volatile("" ::: "memory")
#define WAIT_VM(N) asm volatile("s_waitcnt vmcnt(" #N ")" ::: "memory")
#define BARRIER()                    \
  do {                               \
    CFENCE;                          \
    __builtin_amdgcn_s_barrier();    \
    CFENCE;                          \
  } while (0)

// ---------------------------------------------------------------------------
// 256x256-tile 8-phase pipelined GEMM core (T1+T2+T3+T4+T5), 512 thr
// (8 waves, 2Mx4N), BK=64, per-wave output 128x64 (acc[8][4] f32x4),
// 128 KiB LDS (2 K-tile buffers x (A 256x64 + B 256x64) f16).
//
// DEEP-PREFETCH schedule (m201-faithful: 3 half-tiles in flight, vmcnt(6)):
// every staged load is issued >=3 phases before the wait that drains it.
// Stage legality (WAR), from read-completion points of each buffer region:
//   buf0: B reads done after P1, A reads done after P2
//         -> t+2: h2@P2, h3+h0@P3, h1@P4
//   buf1: B reads done after P5, A reads done after P6
//         -> t+3: h2@P6, h3+h0@P7, h1@P0(next iter)
// Waits at P3/P7: WAIT_VM(6) = keep the 6 newest loads (next tile's
// h2/h3/h0), drain the 8 loads of the tile read next phase.
// Outstanding ledger per wave (2 loads/stage): enter iter with 6;
// P0 +2 =8; P2 +2 =10; P3 +4 =14 -> vmcnt(6) drains t1's 8.  P4 +2 =8;
// P6 +2 =10; P7 +4 =14 -> vmcnt(6) drains t2's 8.  Symmetric.
// Prologue: 7 half-tiles (t0 x4, t1 h2/h3/h0), vmcnt(6) = buf0 landed.
// Last iter: no stages; P3 vmcnt(0).
// ---------------------------------------------------------------------------
template <int EPI>
__device__ __forceinline__ void gemm256_core(
    const f16* __restrict__ A, const f16* __restrict__ B,
    f16* __restrict__ Ch, const float* __restrict__ bias,
    int lda, int ldb, int ldc, int kper, int kbeg, int bm, int bn,
    f16* smp) {
  const int t = threadIdx.x;
  const int wave = t >> 6, lane = t & 63;
  const int wm = (wave >> 2) << 7;  // wave M offset: 0/128
  const int wn = (wave & 3) << 6;   // wave N offset: 0/64/128/192
  const int lrow = lane & 15, lkc = lane >> 4;

  // staging: seg = wave*2+l covers 8 rows of a 128-row half-tile
  const int srow = lane >> 3;
  const int schunk = ((lane & 7) ^ srow) << 3;  // swizzled source chunk (elems)
  const f16* Ag = A + (size_t)(bm + wave * 16 + srow) * lda + kbeg + schunk;
  const f16* Bg = B + (size_t)(bn + wave * 16 + srow) * ldb + kbeg + schunk;

  // swizzled fragment k-offsets (elems within 64-elem row), kk = 0 / 1
  const int co0 = ((lkc ^ (lrow & 7)) << 3);
  const int co1 = (((4 + lkc) ^ (lrow & 7)) << 3);

  floatx4 acc[8][4] = {};
  half8 af[4][2];       // one qm-half of A frags, both kk
  half8 bf[2][2][2];    // [qn][fn][kk] -- both qn halves live

  auto STAGE = [&](int b, int tt, int h) {  // h: 0=A-lo 1=A-hi 2=B-lo 3=B-hi
    if (h < 2) {
      const f16* src = Ag + (size_t)(h * 128) * lda + tt * 64;
      f16* d = smp + (b * 2) * 16384 + h * 8192 + wave * 1024;
      gload_lds16(src, d);
      gload_lds16(src + (size_t)8 * lda, d + 512);
    } else {
      const f16* src = Bg + (size_t)((h - 2) * 128) * ldb + tt * 64;
      f16* d = smp + (b * 2 + 1) * 16384 + (h - 2) * 8192 + wave * 1024;
      gload_lds16(src, d);
      gload_lds16(src + (size_t)8 * ldb, d + 512);
    }
  };
  auto LDA = [&](int b, int qm) {
    const f16* base = smp + (b * 2) * 16384 + (wm + qm * 64 + lrow) * 64;
#pragma unroll
    for (int fm = 0; fm < 4; ++fm) {
      af[fm][0] = *(const half8*)(base + fm * (16 * 64) + co0);
      af[fm][1] = *(const half8*)(base + fm * (16 * 64) + co1);
    }
  };
  auto LDB = [&](int b, int qn) {
    const f16* base = smp + (b * 2 + 1) * 16384 + (wn + qn * 32 + lrow) * 64;
#pragma unroll
    for (int fn = 0; fn < 2; ++fn) {
      bf[qn][fn][0] = *(const half8*)(base + fn * (16 * 64) + co0);
      bf[qn][fn][1] = *(const half8*)(base + fn * (16 * 64) + co1);
    }
  };
  auto MFMAQ = [&](int qm, int qn) {
    __builtin_amdgcn_s_setprio(1);
#pragma unroll
    for (int kk = 0; kk < 2; ++kk)
#pragma unroll
      for (int fm = 0; fm < 4; ++fm)
#pragma unroll
        for (int fn = 0; fn < 2; ++fn)
          acc[qm * 4 + fm][qn * 2 + fn] =
              __builtin_amdgcn_mfma_f32_16x16x32_f16(
                  af[fm][kk], bf[qn][fn][kk], acc[qm * 4 + fm][qn * 2 + fn],
                  0, 0, 0);
    __builtin_amdgcn_s_setprio(0);
  };

  const int NT = kper >> 6;  // K-tiles (even for all call sites)
  const int NI = NT >> 1;

  // prologue: t0 -> buf0 (4 halves), t1 -> buf1 h2,h3,h0 (h1 lands at P0).
  STAGE(0, 0, 0); STAGE(0, 0, 1); STAGE(0, 0, 2); STAGE(0, 0, 3);
  STAGE(1, 1, 2); STAGE(1, 1, 3); STAGE(1, 1, 0);
  WAIT_VM(6);   // buf0 landed; t1's 6 loads stay in flight
  BARRIER();

  for (int i = 0; i < NI; ++i) {
    const bool last = (i == NI - 1);
    const int t1 = 2 * i + 1, t2 = 2 * i + 2, t3 = 2 * i + 3;
    // P0 -- t0 Q(0,0); stage t1's A-hi (buf1 A reads done prev P6)
    LDA(0, 0); LDB(0, 0); STAGE(1, t1, 1);
    BARRIER(); MFMAQ(0, 0); BARRIER();
    // P1 -- t0 Q(0,1)
    LDB(0, 1);
    BARRIER(); MFMAQ(0, 1); BARRIER();
    // P2 -- t0 Q(1,0); buf0 B reads done after P1 -> stage t2 B-lo
    LDA(0, 1);
    if (!last) STAGE(0, t2, 2);
    BARRIER(); MFMAQ(1, 0); BARRIER();
    // P3 -- t0 Q(1,1); buf0 A reads done after P2 -> stage t2 B-hi + A-lo;
    // drain t1 (its newest load, h1, was issued 3 phases ago at P0)
    if (!last) {
      STAGE(0, t2, 3); STAGE(0, t2, 0);
      WAIT_VM(6);
    } else {
      WAIT_VM(0);
    }
    BARRIER(); MFMAQ(1, 1); BARRIER();
    // P4 -- t1 Q(0,0); stage t2 A-hi
    LDA(1, 0); LDB(1, 0);
    if (!last) STAGE(0, t2, 1);
    BARRIER(); MFMAQ(0, 0); BARRIER();
    // P5 -- t1 Q(0,1)
    LDB(1, 1);
    BARRIER(); MFMAQ(0, 1); BARRIER();
    // P6 -- t1 Q(1,0); buf1 B reads done after P5 -> stage t3 B-lo
    LDA(1, 1);
    if (!last) STAGE(1, t3, 2);
    BARRIER(); MFMAQ(1, 0); BARRIER();
    // P7 -- t1 Q(1,1); buf1 A reads done after P6 -> stage t3 B-hi + A-lo;
    // drain t2 (newest load, h1, issued 3 phases ago at P4)
    if (!last) {
      STAGE(1, t3, 3); STAGE(1, t3, 0);
      WAIT_VM(6);
    }
    BARRIER(); MFMAQ(1, 1); BARRIER();
  }

  // epilogue: C/D col = lane&15, row = (lane>>4)*4 + reg
  const int crow0 = bm + wm + lkc * 4;
  const int ccol0 = bn + wn + lrow;
#pragma unroll
  for (int i = 0; i < 8; ++i) {
#pragma unroll
    for (int r2 = 0; r2 < 4; ++r2) {
      const size_t row = (size_t)(crow0 + i * 16 + r2);
#pragma unroll
      for (int j = 0; j < 4; ++j) {
        const int col = ccol0 + j * 16;
        float v = acc[i][j][r2];
        if (EPI == 2) v = fmaxf(v + bias[col], 0.0f);
        Ch[row * (size_t)ldc + col] = (f16)v;
      }
    }
  }
}

// bijective XCD-chunked swizzle (T1): block with HW id `id` (XCD = id%8)
// computes tile nid from its XCD's contiguous chunk.
__device__ __forceinline__ int xcd_swizzle(int id, int nwg) {
  const int q = nwg >> 3, r = nwg & 7;
  const int xcd = id & 7, lin = id >> 3;
  return (xcd < r ? xcd * (q + 1) : r * (q + 1) + (xcd - r) * q) + lin;
}

// ---------------------------------------------------------------------------
// generic NT wrapper: C = A*B^T, split-K via gridDim.z, f16 slabs at
// Ch + z*M*ldc.
// ---------------------------------------------------------------------------
template <int EPI>
__global__ __launch_bounds__(512, 2) void gemm_nt256(
    const f16* __restrict__ A, const f16* __restrict__ B,
    f16* __restrict__ Ch, const float* __restrict__ bias,
    int M, int Nc, int K, int lda, int ldb, int ldc) {
  __shared__ f16 sm[4][256 * 64];
  const int gx = gridDim.x, gy = gridDim.y;
  const int nwg = gx * gy * gridDim.z;
  const int id = blockIdx.x + gx * (blockIdx.y + gy * blockIdx.z);
  const int nid = xcd_swizzle(id, nwg);
  const int bx = nid % gx;
  const int by = (nid / gx) % gy;
  const int bz = nid / (gx * gy);
  const int kper = K / gridDim.z;
  gemm256_core<EPI>(A, B, Ch + (size_t)bz * M * ldc, bias, lda, ldb, ldc,
                    kper, bz * kper, by << 8, bx << 8, &sm[0][0]);
}

// ---------------------------------------------------------------------------
// weight precompose on the 8-phase core: grid (4,4,16).
// z<8: parQK slab zz = Wkb@Wqb^T (K=4096 split 8); z>=8: parVO = WoT@Wvb^T.
// ---------------------------------------------------------------------------
__global__ __launch_bounds__(512, 2) void gemm_pre256(
    const f16* __restrict__ Wkb, const f16* __restrict__ Wqb,
    const f16* __restrict__ WoT, const f16* __restrict__ Wvb,
    f16* __restrict__ parQK, f16* __restrict__ parVO, int D, int H) {
  __shared__ f16 sm[4][256 * 64];
  const int id = blockIdx.x + 4 * (blockIdx.y + 4 * blockIdx.z);
  const int nid = xcd_swizzle(id, 256);
  const int bx = nid & 3, by = (nid >> 2) & 3, z = nid >> 4;
  const int zz = z & 7;
  const f16* A = (z < 8) ? Wkb : WoT;
  const f16* B = (z < 8) ? Wqb : Wvb;
  f16* slab = ((z < 8) ? parQK : parVO) + (size_t)zz * D * D;
  gemm256_core<1>(A, B, slab, nullptr, H, H, D, H / 8, zz * (H / 8),
                  by << 8, bx << 8, &sm[0][0]);
}

// ---------------------------------------------------------------------------
// merged th/xvoT on the 8-phase core: grid (4,32).
// y<16: th = xb@WqkT^T [N,D] (bm=y,bn=x); y>=16: xvoT = WvoT@xb^T [D,N].
// ---------------------------------------------------------------------------
__global__ __launch_bounds__(512, 2) void gemm_dual256(
    const f16* __restrict__ xb, const f16* __restrict__ WqkT,
    const f16* __restrict__ WvoT, f16* __restrict__ th,
    f16* __restrict__ xvoT, int N, int D) {
  __shared__ f16 sm[4][256 * 64];
  const int id = blockIdx.x + 4 * blockIdx.y;
  const int nid = xcd_swizzle(id, 128);
  const int bx = nid & 3, y = nid >> 2;
  if (y < 16)
    gemm256_core<1>(xb, WqkT, th, nullptr, D, D, D, D, 0,
                    y << 8, bx << 8, &sm[0][0]);
  else
    gemm256_core<1>(WvoT, xb, xvoT, nullptr, D, D, N, D, 0,
                    bx << 8, (y - 16) << 8, &sm[0][0]);
}

// ---------------------------------------------------------------------------
// fused input prep (round-3 best-measured variant), grid (1024, 7), block 256.
// z 0..2: transposes via shfl 4x4 transpose + swizzled LDS (r^((c&15)<<2)).
// z 3..6: converts, 4x float4 in, 2x half8 out per lane.
// ---------------------------------------------------------------------------
__global__ void prep_inputs(const float* x, const float* Wq, const float* Wk,
                            const float* Wv, const float* W1, const float* Wo,
                            const float* W2, f16* xb, f16* Wqb, f16* Wkb,
                            f16* Wvb, f16* W1T, f16* WoT, f16* W2T) {
  const int z = blockIdx.y;
  const int b = blockIdx.x;
  const int t = threadIdx.x;
  if (z >= 3) {  // converts
    const float* in = (z == 3) ? x : (z == 4) ? Wq : (z == 5) ? Wk : Wv;
    f16* out = (z == 3) ? xb : (z == 4) ? Wqb : (z == 5) ? Wkb : Wvb;
    const size_t i = ((size_t)b * 256 + t) * 16;
    const float4 a0 = *(const float4*)(in + i);
    const float4 a1 = *(const float4*)(in + i + 4);
    const float4 a2 = *(const float4*)(in + i + 8);
    const float4 a3 = *(const float4*)(in + i + 12);
    half8 v0 = {(f16)a0.x, (f16)a0.y, (f16)a0.z, (f16)a0.w,
                (f16)a1.x, (f16)a1.y, (f16)a1.z, (f16)a1.w};
    half8 v1 = {(f16)a2.x, (f16)a2.y, (f16)a2.z, (f16)a2.w,
                (f16)a3.x, (f16)a3.y, (f16)a3.z, (f16)a3.w};
    *(half8*)(out + i) = v0;
    *(half8*)(out + i + 8) = v1;
    return;
  }
  int R, C, tx, ty;
  const float* in;
  f16* out;
  if (z == 0) {
    R = 1024; C = 4096; in = W1; out = W1T;
    tx = b & 63; ty = b >> 6;
  } else {
    R = 4096; C = 1024; in = (z == 1) ? Wo : W2;
    out = (z == 1) ? WoT : W2T;
    tx = b & 15; ty = b >> 4;
  }
  const int r0 = ty << 6, c0 = tx << 6;
  __shared__ f16 lt[64 * 64];
  const int lr = t >> 4;
  const int lc = t & 15;
  const int q3 = lr & 3;
  const int rb = lr & ~3;
  const int myc = lc * 4 + q3;
#pragma unroll
  for (int rr = 0; rr < 4; ++rr) {
    const int r = lr + rr * 16;
    const float4 f = *(const float4*)(in + (size_t)(r0 + r) * C + c0 + lc * 4);
    float v0 = f.x, v1 = f.y, v2 = f.z, v3 = f.w;
    // 4x4 transpose among lanes {t ^ 16, t ^ 32}: block swap (mask 32)...
    {
      const bool hi = (q3 & 2) != 0;
      float sA = hi ? v0 : v2;
      float sB = hi ? v1 : v3;
      sA = __shfl_xor(sA, 32);
      sB = __shfl_xor(sB, 32);
      if (hi) { v0 = sA; v1 = sB; } else { v2 = sA; v3 = sB; }
    }
    // ...then in-block 2x2 transpose (mask 16)
    {
      const bool od = (q3 & 1) != 0;
      float sC = od ? v0 : v1;
      float sD = od ? v2 : v3;
      sC = __shfl_xor(sC, 16);
      sD = __shfl_xor(sD, 16);
      if (od) { v0 = sC; v2 = sD; } else { v1 = sC; v3 = sD; }
    }
    half4 hv = {(f16)v0, (f16)v1, (f16)v2, (f16)v3};
    const int rbase = rb + rr * 16;
    *(half4*)(lt + myc * 64 + (rbase ^ ((myc & 15) << 2))) = hv;
  }
  __syncthreads();
  const int oc = t >> 3, orr = (t & 7) << 3;
#pragma unroll
  for (int cc = 0; cc < 2; ++cc) {
    const int c = oc + cc * 32;
    const int swz = (c & 15) << 2;
    const half4 ha = *(const half4*)(lt + c * 64 + (orr ^ swz));
    const half4 hb4 = *(const half4*)(lt + c * 64 + ((orr + 4) ^ swz));
    half8 v = {ha[0], ha[1], ha[2], ha[3], hb4[0], hb4[1], hb4[2], hb4[3]};
    *(half8*)(out + (size_t)(c0 + c) * R + r0 + orr) = v;
  }
}

// ---------------------------------------------------------------------------
// merged slab reduce (round-3 exact): first half of blocks sum 8 f16 slabs
// parQK -> WqkT, second half parVO -> WvoT. n = D*D.
// ---------------------------------------------------------------------------
__global__ void reduce_dual(const f16* __restrict__ parQK,
                            const f16* __restrict__ parVO,
                            f16* __restrict__ WqkT, f16* __restrict__ WvoT,
                            int n) {
  const int half = gridDim.x >> 1;
  const bool second = blockIdx.x >= half;
  const f16* par = second ? parVO : parQK;
  f16* out = second ? WvoT : WqkT;
  const int b = second ? blockIdx.x - half : blockIdx.x;
  const int i = (b * 256 + threadIdx.x) * 4;
  float s0 = 0, s1 = 0, s2 = 0, s3 = 0;
#pragma unroll
  for (int z = 0; z < 8; ++z) {
    const half4 p = *(const half4*)(par + (size_t)z * n + i);
    s0 += (float)p[0]; s1 += (float)p[1]; s2 += (float)p[2]; s3 += (float)p[3];
  }
  half4 o = {(f16)s0, (f16)s1, (f16)s2, (f16)s3};
  *(half4*)(out + i) = o;
}

// ---------------------------------------------------------------------------
// row softmax: f16 S[row,:N] -> f16 P. One 256-thread block per row, N=4096.
// ---------------------------------------------------------------------------
__global__ void softmax_rows(const f16* __restrict__ S, f16* __restrict__ P,
                             int N) {
  const int row = blockIdx.x;
  const int t = threadIdx.x;
  const int lane = t & 63, wave = t >> 6;
  const f16* s = S + (size_t)row * N;
  const half8 a = *(const half8*)(s + t * 8);
  const half8 b = *(const half8*)(s + 2048 + t * 8);
  float v[16];
#pragma unroll
  for (int i = 0; i < 8; ++i) {
    v[i] = (float)a[i];
    v[8 + i] = (float)b[i];
  }
  float mx = -1e30f;
#pragma unroll
  for (int i = 0; i < 16; ++i) mx = fmaxf(mx, v[i]);
#pragma unroll
  for (int off = 32; off > 0; off >>= 1) mx = fmaxf(mx, __shfl_xor(mx, off));
  __shared__ float red[8];
  if (lane == 0) red[wave] = mx;
  __syncthreads();
  mx = fmaxf(fmaxf(red[0], red[1]), fmaxf(red[2], red[3]));
  float sum = 0.0f;
#pragma unroll
  for (int i = 0; i < 16; ++i) {
    v[i] = __expf(v[i] - mx);
    sum += v[i];
  }
#pragma unroll
  for (int off = 32; off > 0; off >>= 1) sum += __shfl_xor(sum, off);
  if (lane == 0) red[4 + wave] = sum;
  __syncthreads();
  const float inv = 1.0f / (red[4] + red[5] + red[6] + red[7]);
  f16* p = P + (size_t)row * N;
  half8 oa, ob;
#pragma unroll
  for (int i = 0; i < 8; ++i) {
    oa[i] = (f16)(v[i] * inv);
    ob[i] = (f16)(v[8 + i] * inv);
  }
  *(half8*)(p + t * 8) = oa;
  *(half8*)(p + 2048 + t * 8) = ob;
}

// ---------------------------------------------------------------------------
// fused residual + f16 split-K slab reduce + (optional bias) + LayerNorm.
// One 256-thread block per row, D=1024. NCH compile-time for load ILP.
// ---------------------------------------------------------------------------
template <int NCH>
__global__ void add_ln(const float* __restrict__ a, const f16* __restrict__ b,
                       size_t cs, const float* __restrict__ bias,
                       const float* __restrict__ g, const float* __restrict__ be,
                       float* __restrict__ outf, f16* __restrict__ outh, int D) {
  const int row = blockIdx.x;
  const int t = threadIdx.x;
  const int lane = t & 63, wave = t >> 6;
  const float4 av = *(const float4*)(a + (size_t)row * D + t * 4);
  half4 bv[NCH];
#pragma unroll
  for (int c = 0; c < NCH; ++c)
    bv[c] = *(const half4*)(b + c * cs + (size_t)row * D + t * 4);
  float s[4] = {av.x, av.y, av.z, av.w};
#pragma unroll
  for (int c = 0; c < NCH; ++c) {
    s[0] += (float)bv[c][0]; s[1] += (float)bv[c][1];
    s[2] += (float)bv[c][2]; s[3] += (float)bv[c][3];
  }
  if (bias != nullptr) {
    const float4 bb = *(const float4*)(bias + t * 4);
    s[0] += bb.x; s[1] += bb.y; s[2] += bb.z; s[3] += bb.w;
  }
  float sum = s[0] + s[1] + s[2] + s[3];
  float sq = s[0] * s[0] + s[1] * s[1] + s[2] * s[2] + s[3] * s[3];
#pragma unroll
  for (int off = 32; off > 0; off >>= 1) {
    sum += __shfl_xor(sum, off);
    sq += __shfl_xor(sq, off);
  }
  __shared__ float red[8];
  if (lane == 0) {
    red[wave] = sum;
    red[4 + wave] = sq;
  }
  __syncthreads();
  sum = red[0] + red[1] + red[2] + red[3];
  sq = red[4] + red[5] + red[6] + red[7];
  const float mu = sum / (float)D;
  const float rv = rsqrtf(sq / (float)D - mu * mu + LN_EPS);
  const float4 gv = *(const float4*)(g + t * 4);
  const float4 bev = *(const float4*)(be + t * 4);
  float y0 = (s[0] - mu) * rv * gv.x + bev.x;
  float y1 = (s[1] - mu) * rv * gv.y + bev.y;
  float y2 = (s[2] - mu) * rv * gv.z + bev.z;
  float y3 = (s[3] - mu) * rv * gv.w + bev.w;
  if (outf != nullptr) {
    float4 o = {y0, y1, y2, y3};
    *(float4*)(outf + (size_t)row * D + t * 4) = o;
  }
  if (outh != nullptr) {
    f16* ob = outh + (size_t)row * D + t * 4;
    ob[0] = (f16)y0;
    ob[1] = (f16)y1;
    ob[2] = (f16)y2;
    ob[3] = (f16)y3;
  }
}

// ---------------------------------------------------------------------------
// launch
// ---------------------------------------------------------------------------
extern "C" void kernel_launch(void* const* d_in, const int* in_sizes, int n_in,
                              void* d_out, int out_size, void* d_ws,
                              size_t ws_size, hipStream_t stream) {
  constexpr int N = 4096, D = 1024, H = 4096;
  const float* x = (const float*)d_in[0];
  const float* Wq = (const float*)d_in[1];
  const float* Wk = (const float*)d_in[2];
  const float* Wv = (const float*)d_in[3];
  const float* Wo = (const float*)d_in[4];
  const float* W1 = (const float*)d_in[5];
  const float* b1 = (const float*)d_in[6];
  const float* W2 = (const float*)d_in[7];
  const float* b2 = (const float*)d_in[8];
  const float* g1 = (const float*)d_in[9];
  const float* be1 = (const float*)d_in[10];
  const float* g2 = (const float*)d_in[11];
  const float* be2 = (const float*)d_in[12];
  float* out = (float*)d_out;

  const size_t MB = 1024ull * 1024ull;
  char* w = (char*)d_ws;
  // workspace layout (228 MB used; hazard-checked reuse; offsets in MB):
  f16* xb   = (f16*)(w + 0 * MB);     // 8   [N,D]
  f16* Wqb  = (f16*)(w + 8 * MB);     // 8   [D,H]
  f16* Wkb  = (f16*)(w + 16 * MB);    // 8   [D,H]
  f16* Wvb  = (f16*)(w + 24 * MB);    // 8   [D,H]
  f16* WoT  = (f16*)(w + 32 * MB);    // 8   [D,H]
  f16* W1T  = (f16*)(w + 40 * MB);    // 8   [H,D]
  f16* W2T  = (f16*)(w + 48 * MB);    // 8   [D,H]
  f16* WqkT = (f16*)(w + 56 * MB);    // 2   [D,D] = (Wq@Wk^T)^T
  f16* WvoT = (f16*)(w + 58 * MB);    // 2   [D,D] = (Wv@Wo)^T
  f16* th   = (f16*)(w + 60 * MB);    // 8   [N,D]; dead after S
  f16* xvoT = (f16*)(w + 68 * MB);    // 8   [D,N]
  f16* F1   = (f16*)(w + 76 * MB);    // 32  [N,H]
  f16* Sh   = (f16*)(w + 108 * MB);   // 32  [N,N] f16; dead after softmax
  f16* parA = (f16*)(w + 108 * MB);   // 4x8MB f16 slabs (over dead Sh)
  f16* Pb   = (f16*)(w + 140 * MB);   // 32  [N,N]; dead after attn
  float* hf = (float*)(w + 172 * MB); // 16  [N,D]
  f16* hb   = (f16*)(w + 188 * MB);   // 8   [N,D]
  f16* parQK = (f16*)(w + 196 * MB);  // 16 = 8x2MB f16 slabs; dead after reduce
  f16* parVO = (f16*)(w + 212 * MB);  // 16 = 8x2MB f16 slabs; dead after reduce

  // ---- input prep: 4 converts + 3 transposes, ONE dispatch ----
  prep_inputs<<<dim3(1024, 7), 256, 0, stream>>>(
      x, Wq, Wk, Wv, W1, Wo, W2, xb, Wqb, Wkb, Wvb, W1T, WoT, W2T);

  // ---- weight precomposition (both [D,D] composites, one dispatch) ----
  gemm_pre256<<<dim3(4, 4, 16), 512, 0, stream>>>(
      Wkb, Wqb, WoT, Wvb, parQK, parVO, D, H);
  reduce_dual<<<2 * (D * D) / 1024, 256, 0, stream>>>(parQK, parVO, WqkT,
                                                      WvoT, D * D);

  // ---- attention ----
  // th = xb@WqkT^T [N,D] and xvoT = WvoT@xb^T [D,N], one dispatch
  gemm_dual256<<<dim3(4, 32), 512, 0, stream>>>(xb, WqkT, WvoT, th, xvoT,
                                                N, D);
  // S = th @ xb^T  [N,N] f16 logits (K=1024), 256^2 8-phase kernel
  gemm_nt256<1><<<dim3(N / 256, N / 256, 1), 512, 0, stream>>>(
      th, xb, Sh, nullptr, N, N, D, D, D, N);
  softmax_rows<<<N, 256, 0, stream>>>(Sh, Pb, N);
  // attn partials = Pb @ xvoT^T  [N,D], split-K=4, f16 slabs (over dead Sh)
  gemm_nt256<1><<<dim3(D / 256, N / 256, 4), 512, 0, stream>>>(
      Pb, xvoT, parA, nullptr, N, D, N, N, N, D);
  // h = LN(x + sum(attn partials))
  add_ln<4><<<N, 256, 0, stream>>>(x, parA, (size_t)N * D, nullptr, g1, be1,
                                   hf, hb, D);

  // ---- feed-forward ----
  // F1 = relu(hb @ W1T^T + b1)  [N,H] f16
  gemm_nt256<2><<<dim3(H / 256, N / 256, 1), 512, 0, stream>>>(
      hb, W1T, F1, b1, N, H, D, D, D, H);
  // F2 partials = F1 @ W2T^T  [N,D], split-K=4, f16 slabs
  gemm_nt256<1><<<dim3(D / 256, N / 256, 4), 512, 0, stream>>>(
      F1, W2T, parA, nullptr, N, D, H, H, H, D);
  // out = LN(hf + sum(F2 partials) + b2)
  add_ln<4><<<N, 256, 0, stream>>>(hf, parA, (size_t)N * D, b2, g2, be2,
                                   out, nullptr, D);
}